// Round 12
// baseline (162.813 us; speedup 1.0000x reference)
//
#include <hip/hip_runtime.h>
#include <math.h>

#define BSZ 2
#define LSEQ 2048
#define DMODEL 512
#define DINNER 1024
#define NST 16
#define RDT 32
#define GDBL 64   // RDT + 2*NST
#define NCH 32    // chunks over L
#define CHL 64    // steps per chunk
#define LOG2E 1.4426950408889634f
#define LN2   0.6931471805599453f

typedef unsigned short u16;
typedef unsigned int   u32;
typedef __attribute__((ext_vector_type(8))) __bf16 bf16x8;
typedef __attribute__((ext_vector_type(4))) float  f32x4;

__device__ __forceinline__ u16 f2bf(float f){
  u32 u = __float_as_uint(f);
  u += 0x7fff + ((u >> 16) & 1);
  return (u16)(u >> 16);
}
__device__ __forceinline__ float bf2f(u16 u){ return __uint_as_float((u32)u << 16); }
__device__ __forceinline__ float exp2fast(float x){
  float r; asm("v_exp_f32 %0, %1" : "=v"(r) : "v"(x)); return r;
}
__device__ __forceinline__ float log2fast(float x){
  float r; asm("v_log_f32 %0, %1" : "=v"(r) : "v"(x)); return r;
}
__device__ __forceinline__ float rcpfast(float x){
  float r; asm("v_rcp_f32 %0, %1" : "=v"(r) : "v"(x)); return r;
}
// silu(x) = x / (1 + e^-x), via rcp+exp2 (avoids slow exact-div sequence)
__device__ __forceinline__ float siluf(float x){
  return x * rcpfast(1.f + exp2fast(-x*LOG2E));
}
// softplus(x) = ln(1+e^x), via exp2+log2
__device__ __forceinline__ float softplusf(float x){
  if (x > 20.f) return x;
  return log2fast(1.f + exp2fast(x*LOG2E)) * LN2;
}
// async global->LDS, 16B per lane
__device__ __forceinline__ void gld16(const void* g, void* l){
  __builtin_amdgcn_global_load_lds((const __attribute__((address_space(1))) void*)g,
                                   (__attribute__((address_space(3))) void*)l, 16, 0, 0);
}
// unpack 8 packed bf16 (uint4) -> 8 f32
__device__ __forceinline__ void unpack8(uint4 v, float* f){
  f[0]=__uint_as_float(v.x<<16); f[1]=__uint_as_float(v.x&0xffff0000u);
  f[2]=__uint_as_float(v.y<<16); f[3]=__uint_as_float(v.y&0xffff0000u);
  f[4]=__uint_as_float(v.z<<16); f[5]=__uint_as_float(v.z&0xffff0000u);
  f[6]=__uint_as_float(v.w<<16); f[7]=__uint_as_float(v.w&0xffff0000u);
}
// sum across the 4 lanes of a quad: 2 DPP quad_perm adds
__device__ __forceinline__ float quadsum(float p){
  p += __int_as_float(__builtin_amdgcn_update_dpp(0, __float_as_int(p), 0xB1, 0xf, 0xf, true)); // [1,0,3,2]
  p += __int_as_float(__builtin_amdgcn_update_dpp(0, __float_as_int(p), 0x4E, 0xf, 0xf, true)); // [2,3,0,1]
  return p;
}

// ---------------- K01: weight cvt (blocks 0..1631) + LN1 norm (blocks 1632..1759) ----------------
__global__ void k01_wcvt_ln(const float* __restrict__ Wip, const float* __restrict__ Wop,
                            const float* __restrict__ Wxp, const float* __restrict__ Wdt,
                            u16* __restrict__ wipb, u16* __restrict__ wopb,
                            u16* __restrict__ wxpb, u16* __restrict__ wdtb,
                            const float* __restrict__ x, const float* __restrict__ w1,
                            const float* __restrict__ b1, u16* __restrict__ xnb){
  __shared__ float ss[8][33], qq[8][33];
  __shared__ float muL[32], rsL[32];
  if (blockIdx.x < 1632){
    int idx = blockIdx.x*256 + threadIdx.x;
    int i4 = idx * 4;
    const float* src; u16* dst;
    if (i4 < 1048576){ src = Wip + i4; dst = wipb + i4; }
    else if (i4 < 1048576 + 524288){ int j = i4 - 1048576; src = Wop + j; dst = wopb + j; }
    else if (i4 < 1048576 + 524288 + 65536){ int j = i4 - 1048576 - 524288; src = Wxp + j; dst = wxpb + j; }
    else { int j = i4 - 1048576 - 524288 - 65536; if (j >= 32768) return; src = Wdt + j; dst = wdtb + j; }
    float4 v = *(const float4*)src;
    u32 lo = (u32)f2bf(v.x) | ((u32)f2bf(v.y) << 16);
    u32 hi = (u32)f2bf(v.z) | ((u32)f2bf(v.w) << 16);
    *(uint2*)dst = make_uint2(lo, hi);
    return;
  }
  // LN1: 128 blocks of 32 l; 32 lc x 8 dc (64 d each)
  int blk = blockIdx.x - 1632;
  int b = blk >> 6;
  int l0 = (blk & 63) * 32;
  int t = threadIdx.x;
  int lc = t & 31, dc = t >> 5;
  const float* xb = x + (size_t)b*DMODEL*LSEQ;
  float s=0.f, q=0.f;
  for (int d = dc*64; d < dc*64+64; ++d){
    float v = xb[d*LSEQ + l0 + lc];
    s += v; q += v*v;
  }
  ss[dc][lc]=s; qq[dc][lc]=q;
  __syncthreads();
  if (t < 32){
    float S=0.f,Q=0.f;
    for (int i=0;i<8;++i){S+=ss[i][t];Q+=qq[i][t];}
    float m = S/DMODEL;
    muL[t]=m; rsL[t]=rsqrtf(Q/DMODEL - m*m + 1e-5f);
  }
  __syncthreads();
  float mu = muL[lc], rs = rsL[lc];
  u16* orow = xnb + ((size_t)(b*LSEQ + l0 + lc))*DMODEL;
  for (int d = dc*64; d < dc*64+64; d += 2){
    float v0 = (xb[d*LSEQ + l0 + lc]     - mu)*rs*w1[d]   + b1[d];
    float v1 = (xb[(d+1)*LSEQ + l0 + lc] - mu)*rs*w1[d+1] + b1[d+1];
    *(u32*)&orow[d] = (u32)f2bf(v0) | ((u32)f2bf(v1) << 16);
  }
}

// ---------------- K2: in_proj bf16 MFMA GEMM; outputs bf16 xin & z ----------------
__global__ __launch_bounds__(256) void k2_inproj_mfma(
    const u16* __restrict__ xnb, const u16* __restrict__ wipb,
    u16* __restrict__ xinb, u16* __restrict__ zb){
  __shared__ u16 As[2][4096];
  __shared__ u16 Bs[2][4096];
  int t = threadIdx.x;
  int wid = t >> 6, lane = t & 63;
  int n0 = blockIdx.x * 128, m0 = blockIdx.y * 128;
  int wr = wid >> 1, wc = wid & 1;
  int lr = lane & 15, q = lane >> 4;

  const u16* gA = xnb  + (size_t)(m0 + (t>>2))*DMODEL + (t&3)*8;
  const u16* gB = wipb + (size_t)(n0 + (t>>2))*DMODEL + (t&3)*8;

  f32x4 acc[4][4];
  #pragma unroll
  for (int i=0;i<4;++i)
    #pragma unroll
    for (int j=0;j<4;++j) acc[i][j] = (f32x4){0.f,0.f,0.f,0.f};

  #pragma unroll
  for (int r=0;r<2;++r){
    gld16(gA + (size_t)r*64*DMODEL, &As[0][(wid*64 + r*256)*8]);
    gld16(gB + (size_t)r*64*DMODEL, &Bs[0][(wid*64 + r*256)*8]);
  }
  const int abase = (wr*64 + lr)*32 + q*8;
  const int bbase = (wc*64 + lr)*32 + q*8;

  for (int ks = 0; ks < 16; ++ks){
    int cur = ks & 1;
    __syncthreads();
    if (ks < 15){
      const u16* gA2 = gA + (ks+1)*32;
      const u16* gB2 = gB + (ks+1)*32;
      #pragma unroll
      for (int r=0;r<2;++r){
        gld16(gA2 + (size_t)r*64*DMODEL, &As[cur^1][(wid*64 + r*256)*8]);
        gld16(gB2 + (size_t)r*64*DMODEL, &Bs[cur^1][(wid*64 + r*256)*8]);
      }
    }
    bf16x8 a[4], bv[4];
    #pragma unroll
    for (int mf=0; mf<4; ++mf) a[mf]  = *(const bf16x8*)&As[cur][abase + mf*512];
    #pragma unroll
    for (int nf=0; nf<4; ++nf) bv[nf] = *(const bf16x8*)&Bs[cur][bbase + nf*512];
    #pragma unroll
    for (int mf=0; mf<4; ++mf)
      #pragma unroll
      for (int nf=0; nf<4; ++nf)
        acc[mf][nf] = __builtin_amdgcn_mfma_f32_16x16x32_bf16(a[mf], bv[nf], acc[mf][nf], 0, 0, 0);
  }

  bool half = (n0 >= DINNER);
  u16* outp = half ? zb : xinb;
  int colb = (half ? n0 - DINNER : n0) + wc*64 + lr;
  #pragma unroll
  for (int mf=0; mf<4; ++mf){
    int rowb = m0 + wr*64 + mf*16 + q*4;
    #pragma unroll
    for (int nf=0; nf<4; ++nf){
      f32x4 v = acc[mf][nf];
      int col = colb + nf*16;
      #pragma unroll
      for (int j=0;j<4;++j) outp[(size_t)(rowb+j)*DINNER + col] = f2bf(v[j]);
    }
  }
}

// ---------------- K3: causal depthwise conv (K=4) + SiLU, bf16 in -> bf16 out ----------------
__global__ void k3_conv(const u16* __restrict__ xinb, const float* __restrict__ cw,
                        const float* __restrict__ cb, u16* __restrict__ xc){
  int idx = blockIdx.x*blockDim.x + threadIdx.x;
  int e4 = (idx & (DINNER/4 - 1)) * 4;
  int m = idx >> 8;
  int b = m >> 11; int l = m & (LSEQ-1);
  float4 accb = *(const float4*)&cb[e4];
  float acc[4] = {accb.x, accb.y, accb.z, accb.w};
  #pragma unroll
  for (int k=0;k<4;++k){
    int li = l + k - 3;
    if (li >= 0){
      ushort4 v = *(const ushort4*)&xinb[((size_t)(b*LSEQ+li))*DINNER + e4];
      acc[0] += bf2f(v.x) * cw[(e4+0)*4 + k];
      acc[1] += bf2f(v.y) * cw[(e4+1)*4 + k];
      acc[2] += bf2f(v.z) * cw[(e4+2)*4 + k];
      acc[3] += bf2f(v.w) * cw[(e4+3)*4 + k];
    }
  }
  u32 lo = (u32)f2bf(siluf(acc[0])) | ((u32)f2bf(siluf(acc[1])) << 16);
  u32 hi = (u32)f2bf(siluf(acc[2])) | ((u32)f2bf(siluf(acc[3])) << 16);
  *(uint2*)&xc[(size_t)m*DINNER + e4] = make_uint2(lo, hi);
}

// ---------------- K4: x_proj bf16 MFMA GEMM + fused dt_proj (writes dbl[B,C] + dtb) ----------------
// main: dbl_full[m][g]= xc[m]·Wxp[g] (g 0..63); cols 0..31 (dt_lo) stay in LDS;
// epilogue: dtb[m][d] = softplus(dt_lo[m]·Wdt[d] + bias[d]) via in-block MFMA.
__global__ __launch_bounds__(256) void k4_xproj_dt_mfma(
    const u16* __restrict__ xcbf, const u16* __restrict__ wxpb,
    const u16* __restrict__ wdtb, const float* __restrict__ dtbias,
    float* __restrict__ dbl, u16* __restrict__ dtb){
  __shared__ u16 As[2][4096];
  __shared__ u16 Bs[2][4096];
  int t = threadIdx.x;
  int wid = t >> 6, lane = t & 63;
  int m0 = blockIdx.x * 64;
  int wr = wid >> 1, wc = wid & 1;
  int lr = lane & 15, q = lane >> 4;

  const u16* gA = xcbf + (size_t)(m0 + (t>>2))*DINNER + (t&3)*8;
  const u16* gB = wxpb + (size_t)(t>>2)*DINNER + (t&3)*8;

  f32x4 acc[2][2];
  #pragma unroll
  for (int i=0;i<2;++i)
    #pragma unroll
    for (int j=0;j<2;++j) acc[i][j] = (f32x4){0.f,0.f,0.f,0.f};

  #pragma unroll
  for (int r=0;r<2;++r){
    gld16(gA + r*32, &As[0][(r*256 + wid*64)*8]);
    gld16(gB + r*32, &Bs[0][(r*256 + wid*64)*8]);
  }
  const int abase = (wr*32 + lr)*32 + q*8;
  const int bbase = (wc*32 + lr)*32 + q*8;

  for (int ks = 0; ks < 16; ++ks){
    int cur = ks & 1;
    __syncthreads();
    if (ks < 15){
      const u16* gA2 = gA + (ks+1)*64;
      const u16* gB2 = gB + (ks+1)*64;
      #pragma unroll
      for (int r=0;r<2;++r){
        gld16(gA2 + r*32, &As[cur^1][(r*256 + wid*64)*8]);
        gld16(gB2 + r*32, &Bs[cur^1][(r*256 + wid*64)*8]);
      }
    }
    bf16x8 a[2][2], bv[2][2];
    #pragma unroll
    for (int mf=0; mf<2; ++mf)
      #pragma unroll
      for (int s=0; s<2; ++s) a[mf][s] = *(const bf16x8*)&As[cur][abase + mf*512 + s*2048];
    #pragma unroll
    for (int nf=0; nf<2; ++nf)
      #pragma unroll
      for (int s=0; s<2; ++s) bv[nf][s] = *(const bf16x8*)&Bs[cur][bbase + nf*512 + s*2048];
    #pragma unroll
    for (int s=0; s<2; ++s)
      #pragma unroll
      for (int mf=0; mf<2; ++mf)
        #pragma unroll
        for (int nf=0; nf<2; ++nf)
          acc[mf][nf] = __builtin_amdgcn_mfma_f32_16x16x32_bf16(a[mf][s], bv[nf][s], acc[mf][nf], 0, 0, 0);
  }

  // epilogue: B/C cols (32..63) -> dbl; dt_lo cols (0..31) -> LDS bf16
  u16* dtlo_s = &As[0][0];   // 64 x 32 bf16 (reuses GEMM buffer)
  u16* wdt_s  = &Bs[0][0];   // 128 x 32 bf16 per chunk
  __syncthreads();           // main-loop LDS reads complete before reuse
  #pragma unroll
  for (int mf=0; mf<2; ++mf){
    int rowb = m0 + wr*32 + mf*16 + q*4;
    int rloc = wr*32 + mf*16 + q*4;
    #pragma unroll
    for (int nf=0; nf<2; ++nf){
      f32x4 v = acc[mf][nf];
      int col = wc*32 + nf*16 + lr;
      if (wc == 1){
        #pragma unroll
        for (int j=0;j<4;++j) dbl[(size_t)(rowb+j)*GDBL + col] = v[j];
      } else {
        #pragma unroll
        for (int j=0;j<4;++j) dtlo_s[(rloc+j)*32 + col] = f2bf(v[j]);
      }
    }
  }
  __syncthreads();
  // dt-GEMM: 64(m) x 1024(d) x 32, 8 chunks of 128 d-cols; A-frags fixed
  bf16x8 da[4];
  #pragma unroll
  for (int mf=0; mf<4; ++mf) da[mf] = *(const bf16x8*)&dtlo_s[(mf*16 + lr)*32 + q*8];
  for (int c = 0; c < 8; ++c){
    __syncthreads();   // prior chunk's wdt_s reads done
    #pragma unroll
    for (int r2=0; r2<2; ++r2)
      gld16(wdtb + (size_t)(c*128 + r2*64 + (t>>2))*RDT + (t&3)*8, &wdt_s[r2*2048 + (t>>6)*512]);
    __syncthreads();   // staging complete
    bf16x8 db[2];
    #pragma unroll
    for (int nf=0; nf<2; ++nf) db[nf] = *(const bf16x8*)&wdt_s[(wid*32 + nf*16 + lr)*32 + q*8];
    #pragma unroll
    for (int nf=0; nf<2; ++nf){
      int col = c*128 + wid*32 + nf*16 + lr;
      float bias = dtbias[col];
      #pragma unroll
      for (int mf=0; mf<4; ++mf){
        f32x4 v = __builtin_amdgcn_mfma_f32_16x16x32_bf16(da[mf], db[nf], (f32x4){0.f,0.f,0.f,0.f}, 0, 0, 0);
        int rowb = m0 + mf*16 + q*4;
        #pragma unroll
        for (int j=0;j<4;++j) dtb[(size_t)(rowb+j)*DINNER + col] = f2bf(softplusf(v[j] + bias));
      }
    }
  }
}

// ---------------- K6a pass1: chunk summaries; 64d x 4ng threads, 4 h-states/thread ----------------
__global__ __launch_bounds__(256) void k6a_pass1(
    const float* __restrict__ dblg, const u16* __restrict__ xcg, const u16* __restrict__ dtg,
    const float* __restrict__ Alog,
    float* __restrict__ hend, float* __restrict__ dchunk){
  int blk = blockIdx.x;
  int b = blk >> 9;
  int dblk = (blk >> 5) & 15;
  int chunk = blk & 31;
  int d0 = dblk * 64;
  int t = threadIdx.x;
  int d = t >> 2, ng = t & 3;

  float4 Adn2;
  {
    float4 al = *(const float4*)&Alog[(d0+d)*NST + ng*4];
    Adn2.x = -__expf(al.x)*LOG2E; Adn2.y = -__expf(al.y)*LOG2E;
    Adn2.z = -__expf(al.z)*LOG2E; Adn2.w = -__expf(al.w)*LOG2E;
  }
  float h0=0.f, h1=0.f, h2=0.f, h3=0.f, S=0.f;

  __shared__ float dts[32][64];
  __shared__ float xcs[32][64];
  __shared__ float Bst[32][16];

  for (int sub = 0; sub < CHL/32; ++sub){
    int l0 = chunk*CHL + sub*32;
    __syncthreads();
    { // stage dt, xc (bf16x8), B
      int r = t >> 3, c8 = t & 7;
      size_t row = (size_t)(b*LSEQ + l0 + r);
      uint4 dv = *(const uint4*)&dtg[row*DINNER + d0 + c8*8];
      uint4 xv = *(const uint4*)&xcg[row*DINNER + d0 + c8*8];
      float df[8], xf[8];
      unpack8(dv, df); unpack8(xv, xf);
      *(float4*)&dts[r][c8*8]   = make_float4(df[0],df[1],df[2],df[3]);
      *(float4*)&dts[r][c8*8+4] = make_float4(df[4],df[5],df[6],df[7]);
      *(float4*)&xcs[r][c8*8]   = make_float4(xf[0],xf[1],xf[2],xf[3]);
      *(float4*)&xcs[r][c8*8+4] = make_float4(xf[4],xf[5],xf[6],xf[7]);
      if (t < 128){
        int rB = t >> 2, qB = t & 3;
        *(float4*)&Bst[rB][qB*4] = *(const float4*)&dblg[((size_t)(b*LSEQ + l0 + rB))*GDBL + RDT + qB*4];
      }
    }
    __syncthreads();
    #pragma unroll 4
    for (int r = 0; r < 32; ++r){
      float dtv = dts[r][d];
      float xcv = xcs[r][d];
      float4 Bv = *(const float4*)&Bst[r][ng*4];
      float u = dtv * xcv;
      h0 = exp2fast(dtv*Adn2.x)*h0 + u*Bv.x;
      h1 = exp2fast(dtv*Adn2.y)*h1 + u*Bv.y;
      h2 = exp2fast(dtv*Adn2.z)*h2 + u*Bv.z;
      h3 = exp2fast(dtv*Adn2.w)*h3 + u*Bv.w;
      S += dtv;
    }
  }
  size_t cix = ((size_t)(b*NCH + chunk)*DINNER + d0 + d)*NST + ng*4;
  *(float4*)&hend[cix]   = make_float4(h0, h1, h2, h3);
  *(float4*)&dchunk[cix] = make_float4(exp2fast(Adn2.x*S), exp2fast(Adn2.y*S),
                                       exp2fast(Adn2.z*S), exp2fast(Adn2.w*S));
}

// ---------------- K6c pass2: seeded scan; quad_perm n-reduce; gated bf16 y out ----------------
__global__ __launch_bounds__(256) void k6c_pass2(
    const float* __restrict__ dblg, const u16* __restrict__ xcg, const u16* __restrict__ zg,
    const u16* __restrict__ dtg,
    const float* __restrict__ Alog, const float* __restrict__ Dp,
    const float* __restrict__ hend, const float* __restrict__ dchk,
    u16* __restrict__ ybf){
  int blk = blockIdx.x;
  int b = blk >> 9;
  int dblk = (blk >> 5) & 15;
  int chunk = blk & 31;
  int d0 = dblk * 64;
  int t = threadIdx.x;
  int d = t >> 2, ng = t & 3;

  float4 Adn2;
  {
    float4 al = *(const float4*)&Alog[(d0+d)*NST + ng*4];
    Adn2.x = -__expf(al.x)*LOG2E; Adn2.y = -__expf(al.y)*LOG2E;
    Adn2.z = -__expf(al.z)*LOG2E; Adn2.w = -__expf(al.w)*LOG2E;
  }

  // inline h0: exclusive prefix over chunk summaries (float4 per step)
  float h0=0.f, h1=0.f, h2=0.f, h3=0.f;
  {
    size_t base = ((size_t)(b*NCH)*DINNER + d0 + d)*NST + ng*4;
    for (int c = 0; c < chunk; ++c){
      size_t ix = base + (size_t)c*DINNER*NST;
      float4 hv = *(const float4*)&hend[ix];
      float4 dv = *(const float4*)&dchk[ix];
      h0 = dv.x*h0 + hv.x; h1 = dv.y*h1 + hv.y;
      h2 = dv.z*h2 + hv.z; h3 = dv.w*h3 + hv.w;
    }
  }

  __shared__ float dts[32][64];
  __shared__ float xcs[32][64];
  __shared__ float BCs[32][32];   // B cols 0..15, C cols 16..31
  __shared__ float ys[32][64];
  __shared__ float Dps[64];

  if (t < 64) Dps[t] = Dp[d0 + t];

  for (int sub = 0; sub < CHL/32; ++sub){
    int l0 = chunk*CHL + sub*32;
    __syncthreads();
    { // stage dt, xc (bf16x8), B+C
      int r = t >> 3, c8 = t & 7;
      size_t row = (size_t)(b*LSEQ + l0 + r);
      uint4 dv = *(const uint4*)&dtg[row*DINNER + d0 + c8*8];
      uint4 xv = *(const uint4*)&xcg[row*DINNER + d0 + c8*8];
      float df[8], xf[8];
      unpack8(dv, df); unpack8(xv, xf);
      *(float4*)&dts[r][c8*8]   = make_float4(df[0],df[1],df[2],df[3]);
      *(float4*)&dts[r][c8*8+4] = make_float4(df[4],df[5],df[6],df[7]);
      *(float4*)&xcs[r][c8*8]   = make_float4(xf[0],xf[1],xf[2],xf[3]);
      *(float4*)&xcs[r][c8*8+4] = make_float4(xf[4],xf[5],xf[6],xf[7]);
      *(float4*)&BCs[r][c8*4]   = *(const float4*)&dblg[row*GDBL + RDT + c8*4];
    }
    __syncthreads();
    #pragma unroll 4
    for (int r = 0; r < 32; ++r){
      float dtv = dts[r][d];
      float xcv = xcs[r][d];
      float4 Bv = *(const float4*)&BCs[r][ng*4];
      float4 Cv = *(const float4*)&BCs[r][16 + ng*4];
      float u = dtv * xcv;
      h0 = exp2fast(dtv*Adn2.x)*h0 + u*Bv.x;
      h1 = exp2fast(dtv*Adn2.y)*h1 + u*Bv.y;
      h2 = exp2fast(dtv*Adn2.z)*h2 + u*Bv.z;
      h3 = exp2fast(dtv*Adn2.w)*h3 + u*Bv.w;
      float p = h0*Cv.x + h1*Cv.y + h2*Cv.z + h3*Cv.w;
      p = quadsum(p);
      if (ng == 0) ys[r][d] = p;
    }
    __syncthreads();
    { // gate + bf16 write (B,L,E)
      int r = t >> 3, c8 = t & 7;
      size_t row = (size_t)(b*LSEQ + l0 + r);
      uint4 zv = *(const uint4*)&zg[row*DINNER + d0 + c8*8];
      float zf[8]; unpack8(zv, zf);
      float4 s0 = *(const float4*)&ys[r][c8*8];
      float4 s1 = *(const float4*)&ys[r][c8*8+4];
      float4 x0 = *(const float4*)&xcs[r][c8*8];
      float4 x1 = *(const float4*)&xcs[r][c8*8+4];
      float4 D0 = *(const float4*)&Dps[c8*8];
      float4 D1 = *(const float4*)&Dps[c8*8+4];
      float y0 = (s0.x + x0.x*D0.x)*siluf(zf[0]);
      float y1 = (s0.y + x0.y*D0.y)*siluf(zf[1]);
      float y2 = (s0.z + x0.z*D0.z)*siluf(zf[2]);
      float y3 = (s0.w + x0.w*D0.w)*siluf(zf[3]);
      float y4 = (s1.x + x1.x*D1.x)*siluf(zf[4]);
      float y5 = (s1.y + x1.y*D1.y)*siluf(zf[5]);
      float y6 = (s1.z + x1.z*D1.z)*siluf(zf[6]);
      float y7 = (s1.w + x1.w*D1.w)*siluf(zf[7]);
      uint4 o;
      o.x = (u32)f2bf(y0) | ((u32)f2bf(y1) << 16);
      o.y = (u32)f2bf(y2) | ((u32)f2bf(y3) << 16);
      o.z = (u32)f2bf(y4) | ((u32)f2bf(y5) << 16);
      o.w = (u32)f2bf(y6) | ((u32)f2bf(y7) << 16);
      *(uint4*)&ybf[row*DINNER + d0 + c8*8] = o;
    }
  }
}

// ---------------- K7: out_proj bf16 MFMA GEMM, TRANSPOSED bf16 output (B,DMODEL,L) ----------------
__global__ __launch_bounds__(256) void k7_outproj_mfma(
    const u16* __restrict__ ybf, const u16* __restrict__ wopb, u16* __restrict__ xmTb){
  __shared__ u16 As[2][4096];
  __shared__ u16 Bs[2][4096];
  int t = threadIdx.x;
  int wid = t >> 6, lane = t & 63;
  int n0 = blockIdx.x * 64, m0 = blockIdx.y * 64;
  int b  = m0 >> 11;
  int l0 = m0 & (LSEQ-1);
  int wr = wid >> 1, wc = wid & 1;
  int lr = lane & 15, q = lane >> 4;

  const u16* gA = ybf  + (size_t)(m0 + (t>>2))*DINNER + (t&3)*8;
  const u16* gB = wopb + (size_t)(n0 + (t>>2))*DINNER + (t&3)*8;

  f32x4 acc[2][2];
  #pragma unroll
  for (int i=0;i<2;++i)
    #pragma unroll
    for (int j=0;j<2;++j) acc[i][j] = (f32x4){0.f,0.f,0.f,0.f};

  #pragma unroll
  for (int r=0;r<2;++r){
    gld16(gA + r*32, &As[0][(r*256 + wid*64)*8]);
    gld16(gB + r*32, &Bs[0][(r*256 + wid*64)*8]);
  }
  const int abase = (wr*32 + lr)*32 + q*8;
  const int bbase = (wc*32 + lr)*32 + q*8;

  for (int ks = 0; ks < 16; ++ks){
    int cur = ks & 1;
    __syncthreads();
    if (ks < 15){
      const u16* gA2 = gA + (ks+1)*64;
      const u16* gB2 = gB + (ks+1)*64;
      #pragma unroll
      for (int r=0;r<2;++r){
        gld16(gA2 + r*32, &As[cur^1][(r*256 + wid*64)*8]);
        gld16(gB2 + r*32, &Bs[cur^1][(r*256 + wid*64)*8]);
      }
    }
    bf16x8 a[2][2], bv[2][2];
    #pragma unroll
    for (int mf=0; mf<2; ++mf)
      #pragma unroll
      for (int s=0; s<2; ++s) a[mf][s] = *(const bf16x8*)&As[cur][abase + mf*512 + s*2048];
    #pragma unroll
    for (int nf=0; nf<2; ++nf)
      #pragma unroll
      for (int s=0; s<2; ++s) bv[nf][s] = *(const bf16x8*)&Bs[cur][bbase + nf*512 + s*2048];
    #pragma unroll
    for (int s=0; s<2; ++s)
      #pragma unroll
      for (int mf=0; mf<2; ++mf)
        #pragma unroll
        for (int nf=0; nf<2; ++nf)
          acc[mf][nf] = __builtin_amdgcn_mfma_f32_16x16x32_bf16(a[mf][s], bv[nf][s], acc[mf][nf], 0, 0, 0);
  }

  // transposed bf16 store: 4 acc elements = 4 consecutive l -> one uint2 (8B)
  #pragma unroll
  for (int mf=0; mf<2; ++mf){
    int lrow = l0 + wr*32 + mf*16 + q*4;
    #pragma unroll
    for (int nf=0; nf<2; ++nf){
      f32x4 v = acc[mf][nf];
      int col = n0 + wc*32 + nf*16 + lr;
      u32 lo = (u32)f2bf(v[0]) | ((u32)f2bf(v[1]) << 16);
      u32 hi = (u32)f2bf(v[2]) | ((u32)f2bf(v[3]) << 16);
      *(uint2*)&xmTb[((size_t)(b*DMODEL + col))*LSEQ + lrow] = make_uint2(lo, hi);
    }
  }
}

// ---------------- K8: fused LN2 (stats + apply), 16-l blocks ----------------
__global__ void k8_fused(const float* __restrict__ x, const u16* __restrict__ xmTb,
                         const float* __restrict__ w2, const float* __restrict__ b2,
                         float* __restrict__ out){
  int blk = blockIdx.x;
  int b = blk >> 7;
  int l0 = (blk & 127) * 16;
  int t = threadIdx.x;
  int lc = t & 15, dc = t >> 4;
  const float* xb = x    + (size_t)b*DMODEL*LSEQ + l0 + lc;
  const u16*   xt = xmTb + (size_t)b*DMODEL*LSEQ + l0 + lc;
  float s=0.f, q=0.f;
  for (int d = dc*32; d < dc*32+32; ++d){
    float v = xb[d*LSEQ] + bf2f(xt[d*LSEQ]);
    s += v; q += v*v;
  }
  __shared__ float ss[16][17], qq[16][17];
  __shared__ float muL[16], rsL[16];
  ss[dc][lc]=s; qq[dc][lc]=q;
  __syncthreads();
  if (t < 16){
    float S=0.f,Q=0.f;
    for (int i=0;i<16;++i){S+=ss[i][t];Q+=qq[i][t];}
    float m = S/DMODEL;
    muL[t]=m; rsL[t]=rsqrtf(Q/DMODEL - m*m + 1e-5f);
  }
  __syncthreads();
  float mu = muL[lc], rs = rsL[lc];
  float* ob = out + (size_t)b*DMODEL*LSEQ + l0 + lc;
  for (int d = dc*32; d < dc*32+32; ++d){
    float v = xb[d*LSEQ] + bf2f(xt[d*LSEQ]);
    ob[d*LSEQ] = (v - mu)*rs*w2[d] + b2[d];
  }
}

extern "C" void kernel_launch(void* const* d_in, const int* in_sizes, int n_in,
                              void* d_out, int out_size, void* d_ws, size_t ws_size,
                              hipStream_t stream) {
  const float* x      = (const float*)d_in[0];
  const float* n1w    = (const float*)d_in[1];
  const float* n1b    = (const float*)d_in[2];
  const float* n2w    = (const float*)d_in[3];
  const float* n2b    = (const float*)d_in[4];
  const float* Wip    = (const float*)d_in[5];
  const float* cw     = (const float*)d_in[6];
  const float* cb     = (const float*)d_in[7];
  const float* Wxp    = (const float*)d_in[8];
  const float* Wdt    = (const float*)d_in[9];
  const float* dtbias = (const float*)d_in[10];
  const float* Alog   = (const float*)d_in[11];
  const float* Dp     = (const float*)d_in[12];
  const float* Wop    = (const float*)d_in[13];
  float* out = (float*)d_out;

  // Workspace layout (float offsets), ~62 MB total
  float* ws = (float*)d_ws;
  size_t o = 0;
  u16*  xinb = (u16*)(ws + o); o += 2097152;   // (B,L,E) bf16
  u16*  zb   = (u16*)(ws + o); o += 2097152;   // (B,L,E) bf16
  u16*  xcb  = (u16*)(ws + o); o += 2097152;   // (B,L,E) bf16
  u16*  ybf  = (u16*)(ws + o); o += 2097152;   // (B,L,E) bf16
  u16*  dtb  = (u16*)(ws + o); o += 2097152;   // (B,L,E) bf16 dt
  u16*  xnb  = (u16*)(ws + o); o += 1048576;   // (B,L,D) bf16
  u16*  wipb = (u16*)(ws + o); o += 524288;    // (2048,512) bf16
  u16*  wopb = (u16*)(ws + o); o += 262144;    // (512,1024) bf16
  u16*  wxpb = (u16*)(ws + o); o += 32768;     // (64,1024) bf16
  u16*  wdtb = (u16*)(ws + o); o += 16384;     // (1024,32) bf16
  float* dbl  = ws + o; o += 262144;           // (B,L,64) fp32 (cols 32..63 used)
  float* hend = ws + o; o += 1048576;          // (B,NCH,E,NST)
  float* dchk = ws + o; o += 1048576;
  u16*  xmTb  = (u16*)(ws + o); o += 1048576;  // (B,DMODEL,L) bf16

  k01_wcvt_ln  <<<dim3(1760),        dim3(256), 0, stream>>>(Wip, Wop, Wxp, Wdt, wipb, wopb, wxpb, wdtb,
                                                             x, n1w, n1b, xnb);
  k2_inproj_mfma<<<dim3(16,32),      dim3(256), 0, stream>>>(xnb, wipb, xinb, zb);
  k3_conv      <<<dim3(4096),        dim3(256), 0, stream>>>(xinb, cw, cb, xcb);
  k4_xproj_dt_mfma<<<dim3(64),       dim3(256), 0, stream>>>(xcb, wxpb, wdtb, dtbias, dbl, dtb);
  k6a_pass1    <<<dim3(BSZ*16*NCH),  dim3(256), 0, stream>>>(dbl, xcb, dtb, Alog, hend, dchk);
  k6c_pass2    <<<dim3(BSZ*16*NCH),  dim3(256), 0, stream>>>(dbl, xcb, zb, dtb, Alog, Dp, hend, dchk, ybf);
  k7_outproj_mfma<<<dim3(8,64),      dim3(256), 0, stream>>>(ybf, wopb, xmTb);
  k8_fused     <<<dim3(BSZ*128),     dim3(256), 0, stream>>>(x, xmTb, n2w, n2b, out);
}

// Round 13
// 148.882 us; speedup vs baseline: 1.0936x; 1.0936x over previous
//
#include <hip/hip_runtime.h>
#include <math.h>

#define BSZ 2
#define LSEQ 2048
#define DMODEL 512
#define DINNER 1024
#define NST 16
#define RDT 32
#define GDBL 64   // RDT + 2*NST
#define NCH 32    // chunks over L
#define CHL 64    // steps per chunk
#define LOG2E 1.4426950408889634f
#define LN2   0.6931471805599453f

typedef unsigned short u16;
typedef unsigned int   u32;
typedef __attribute__((ext_vector_type(8))) __bf16 bf16x8;
typedef __attribute__((ext_vector_type(4))) float  f32x4;

__device__ __forceinline__ u16 f2bf(float f){
  u32 u = __float_as_uint(f);
  u += 0x7fff + ((u >> 16) & 1);
  return (u16)(u >> 16);
}
__device__ __forceinline__ float bf2f(u16 u){ return __uint_as_float((u32)u << 16); }
__device__ __forceinline__ float exp2fast(float x){
  float r; asm("v_exp_f32 %0, %1" : "=v"(r) : "v"(x)); return r;
}
__device__ __forceinline__ float log2fast(float x){
  float r; asm("v_log_f32 %0, %1" : "=v"(r) : "v"(x)); return r;
}
__device__ __forceinline__ float rcpfast(float x){
  float r; asm("v_rcp_f32 %0, %1" : "=v"(r) : "v"(x)); return r;
}
// silu(x) = x * rcp(1 + 2^(-x*log2e))
__device__ __forceinline__ float siluf(float x){
  return x * rcpfast(1.f + exp2fast(-x*LOG2E));
}
// softplus(x) = log2(1 + 2^(x*log2e)) * ln2
__device__ __forceinline__ float softplusf(float x){
  if (x > 20.f) return x;
  return log2fast(1.f + exp2fast(x*LOG2E)) * LN2;
}
// async global->LDS, 16B per lane
__device__ __forceinline__ void gld16(const void* g, void* l){
  __builtin_amdgcn_global_load_lds((const __attribute__((address_space(1))) void*)g,
                                   (__attribute__((address_space(3))) void*)l, 16, 0, 0);
}
// unpack 8 packed bf16 (uint4) -> 8 f32
__device__ __forceinline__ void unpack8(uint4 v, float* f){
  f[0]=__uint_as_float(v.x<<16); f[1]=__uint_as_float(v.x&0xffff0000u);
  f[2]=__uint_as_float(v.y<<16); f[3]=__uint_as_float(v.y&0xffff0000u);
  f[4]=__uint_as_float(v.z<<16); f[5]=__uint_as_float(v.z&0xffff0000u);
  f[6]=__uint_as_float(v.w<<16); f[7]=__uint_as_float(v.w&0xffff0000u);
}
// sum across the 4 lanes of a quad: 2 DPP quad_perm adds
__device__ __forceinline__ float quadsum(float p){
  p += __int_as_float(__builtin_amdgcn_update_dpp(0, __float_as_int(p), 0xB1, 0xf, 0xf, true)); // [1,0,3,2]
  p += __int_as_float(__builtin_amdgcn_update_dpp(0, __float_as_int(p), 0x4E, 0xf, 0xf, true)); // [2,3,0,1]
  return p;
}

// ---------------- K01: weight cvt (blocks 0..1631) + LN1 norm (blocks 1632..1759) ----------------
__global__ void k01_wcvt_ln(const float* __restrict__ Wip, const float* __restrict__ Wop,
                            const float* __restrict__ Wxp, const float* __restrict__ Wdt,
                            u16* __restrict__ wipb, u16* __restrict__ wopb,
                            u16* __restrict__ wxpb, u16* __restrict__ wdtb,
                            const float* __restrict__ x, const float* __restrict__ w1,
                            const float* __restrict__ b1, u16* __restrict__ xnb){
  __shared__ float ss[8][33], qq[8][33];
  __shared__ float muL[32], rsL[32];
  if (blockIdx.x < 1632){
    int idx = blockIdx.x*256 + threadIdx.x;
    int i4 = idx * 4;
    const float* src; u16* dst;
    if (i4 < 1048576){ src = Wip + i4; dst = wipb + i4; }
    else if (i4 < 1048576 + 524288){ int j = i4 - 1048576; src = Wop + j; dst = wopb + j; }
    else if (i4 < 1048576 + 524288 + 65536){ int j = i4 - 1048576 - 524288; src = Wxp + j; dst = wxpb + j; }
    else { int j = i4 - 1048576 - 524288 - 65536; if (j >= 32768) return; src = Wdt + j; dst = wdtb + j; }
    float4 v = *(const float4*)src;
    u32 lo = (u32)f2bf(v.x) | ((u32)f2bf(v.y) << 16);
    u32 hi = (u32)f2bf(v.z) | ((u32)f2bf(v.w) << 16);
    *(uint2*)dst = make_uint2(lo, hi);
    return;
  }
  // LN1: 128 blocks of 32 l; 32 lc x 8 dc (64 d each)
  int blk = blockIdx.x - 1632;
  int b = blk >> 6;
  int l0 = (blk & 63) * 32;
  int t = threadIdx.x;
  int lc = t & 31, dc = t >> 5;
  const float* xb = x + (size_t)b*DMODEL*LSEQ;
  float s=0.f, q=0.f;
  for (int d = dc*64; d < dc*64+64; ++d){
    float v = xb[d*LSEQ + l0 + lc];
    s += v; q += v*v;
  }
  ss[dc][lc]=s; qq[dc][lc]=q;
  __syncthreads();
  if (t < 32){
    float S=0.f,Q=0.f;
    for (int i=0;i<8;++i){S+=ss[i][t];Q+=qq[i][t];}
    float m = S/DMODEL;
    muL[t]=m; rsL[t]=rsqrtf(Q/DMODEL - m*m + 1e-5f);
  }
  __syncthreads();
  float mu = muL[lc], rs = rsL[lc];
  u16* orow = xnb + ((size_t)(b*LSEQ + l0 + lc))*DMODEL;
  for (int d = dc*64; d < dc*64+64; d += 2){
    float v0 = (xb[d*LSEQ + l0 + lc]     - mu)*rs*w1[d]   + b1[d];
    float v1 = (xb[(d+1)*LSEQ + l0 + lc] - mu)*rs*w1[d+1] + b1[d+1];
    *(u32*)&orow[d] = (u32)f2bf(v0) | ((u32)f2bf(v1) << 16);
  }
}

// ---------------- K2: in_proj bf16 MFMA GEMM, BK=64 (8 K-steps, half the barriers) ----------------
__global__ __launch_bounds__(256) void k2_inproj_mfma(
    const u16* __restrict__ xnb, const u16* __restrict__ wipb,
    u16* __restrict__ xinb, u16* __restrict__ zb){
  __shared__ u16 As[2][8192];   // 128 rows x 64 k
  __shared__ u16 Bs[2][8192];
  int t = threadIdx.x;
  int wid = t >> 6, lane = t & 63;
  int n0 = blockIdx.x * 128, m0 = blockIdx.y * 128;
  int wr = wid >> 1, wc = wid & 1;
  int lr = lane & 15, q = lane >> 4;

  // staging: round r covers rows r*32..r*32+31; thread row (t>>3), col (t&7)*8
  const u16* gA = xnb  + (size_t)(m0 + (t>>3))*DMODEL + (t&7)*8;
  const u16* gB = wipb + (size_t)(n0 + (t>>3))*DMODEL + (t&7)*8;

  f32x4 acc[4][4];
  #pragma unroll
  for (int i=0;i<4;++i)
    #pragma unroll
    for (int j=0;j<4;++j) acc[i][j] = (f32x4){0.f,0.f,0.f,0.f};

  #pragma unroll
  for (int r=0;r<4;++r){
    gld16(gA + (size_t)r*32*DMODEL, &As[0][r*2048 + wid*512]);
    gld16(gB + (size_t)r*32*DMODEL, &Bs[0][r*2048 + wid*512]);
  }
  const int abase = (wr*64 + lr)*64 + q*8;
  const int bbase = (wc*64 + lr)*64 + q*8;

  for (int ks = 0; ks < 8; ++ks){
    int cur = ks & 1;
    __syncthreads();   // staging into buf[cur] complete; prior reads of buf[cur^1] done
    if (ks < 7){
      const u16* gA2 = gA + (ks+1)*64;
      const u16* gB2 = gB + (ks+1)*64;
      #pragma unroll
      for (int r=0;r<4;++r){
        gld16(gA2 + (size_t)r*32*DMODEL, &As[cur^1][r*2048 + wid*512]);
        gld16(gB2 + (size_t)r*32*DMODEL, &Bs[cur^1][r*2048 + wid*512]);
      }
    }
    bf16x8 a[4][2], bv[4][2];
    #pragma unroll
    for (int mf=0; mf<4; ++mf)
      #pragma unroll
      for (int s=0; s<2; ++s) a[mf][s] = *(const bf16x8*)&As[cur][abase + mf*1024 + s*32];
    #pragma unroll
    for (int nf=0; nf<4; ++nf)
      #pragma unroll
      for (int s=0; s<2; ++s) bv[nf][s] = *(const bf16x8*)&Bs[cur][bbase + nf*1024 + s*32];
    #pragma unroll
    for (int s=0; s<2; ++s)
      #pragma unroll
      for (int mf=0; mf<4; ++mf)
        #pragma unroll
        for (int nf=0; nf<4; ++nf)
          acc[mf][nf] = __builtin_amdgcn_mfma_f32_16x16x32_bf16(a[mf][s], bv[nf][s], acc[mf][nf], 0, 0, 0);
  }

  bool half = (n0 >= DINNER);
  u16* outp = half ? zb : xinb;
  int colb = (half ? n0 - DINNER : n0) + wc*64 + lr;
  #pragma unroll
  for (int mf=0; mf<4; ++mf){
    int rowb = m0 + wr*64 + mf*16 + q*4;
    #pragma unroll
    for (int nf=0; nf<4; ++nf){
      f32x4 v = acc[mf][nf];
      int col = colb + nf*16;
      #pragma unroll
      for (int j=0;j<4;++j) outp[(size_t)(rowb+j)*DINNER + col] = f2bf(v[j]);
    }
  }
}

// ---------------- K3: causal depthwise conv (K=4) + SiLU, bf16 in -> bf16 out ----------------
__global__ void k3_conv(const u16* __restrict__ xinb, const float* __restrict__ cw,
                        const float* __restrict__ cb, u16* __restrict__ xc){
  int idx = blockIdx.x*blockDim.x + threadIdx.x;
  int e4 = (idx & (DINNER/4 - 1)) * 4;
  int m = idx >> 8;
  int b = m >> 11; int l = m & (LSEQ-1);
  float4 accb = *(const float4*)&cb[e4];
  float acc[4] = {accb.x, accb.y, accb.z, accb.w};
  #pragma unroll
  for (int k=0;k<4;++k){
    int li = l + k - 3;
    if (li >= 0){
      ushort4 v = *(const ushort4*)&xinb[((size_t)(b*LSEQ+li))*DINNER + e4];
      acc[0] += bf2f(v.x) * cw[(e4+0)*4 + k];
      acc[1] += bf2f(v.y) * cw[(e4+1)*4 + k];
      acc[2] += bf2f(v.z) * cw[(e4+2)*4 + k];
      acc[3] += bf2f(v.w) * cw[(e4+3)*4 + k];
    }
  }
  u32 lo = (u32)f2bf(siluf(acc[0])) | ((u32)f2bf(siluf(acc[1])) << 16);
  u32 hi = (u32)f2bf(siluf(acc[2])) | ((u32)f2bf(siluf(acc[3])) << 16);
  *(uint2*)&xc[(size_t)m*DINNER + e4] = make_uint2(lo, hi);
}

// ---------------- K4: x_proj bf16 MFMA GEMM (+bf16 dt_lo side output) ----------------
__global__ __launch_bounds__(256) void k4_xproj_mfma(
    const u16* __restrict__ xcbf, const u16* __restrict__ wxpb,
    float* __restrict__ dbl, u16* __restrict__ dtlob){
  __shared__ u16 As[2][4096];
  __shared__ u16 Bs[2][4096];
  int t = threadIdx.x;
  int wid = t >> 6, lane = t & 63;
  int m0 = blockIdx.x * 64;
  int wr = wid >> 1, wc = wid & 1;
  int lr = lane & 15, q = lane >> 4;

  const u16* gA = xcbf + (size_t)(m0 + (t>>2))*DINNER + (t&3)*8;
  const u16* gB = wxpb + (size_t)(t>>2)*DINNER + (t&3)*8;

  f32x4 acc[2][2];
  #pragma unroll
  for (int i=0;i<2;++i)
    #pragma unroll
    for (int j=0;j<2;++j) acc[i][j] = (f32x4){0.f,0.f,0.f,0.f};

  #pragma unroll
  for (int r=0;r<2;++r){
    gld16(gA + r*32, &As[0][(r*256 + wid*64)*8]);
    gld16(gB + r*32, &Bs[0][(r*256 + wid*64)*8]);
  }
  const int abase = (wr*32 + lr)*32 + q*8;
  const int bbase = (wc*32 + lr)*32 + q*8;

  for (int ks = 0; ks < 16; ++ks){
    int cur = ks & 1;
    __syncthreads();
    if (ks < 15){
      const u16* gA2 = gA + (ks+1)*64;
      const u16* gB2 = gB + (ks+1)*64;
      #pragma unroll
      for (int r=0;r<2;++r){
        gld16(gA2 + r*32, &As[cur^1][(r*256 + wid*64)*8]);
        gld16(gB2 + r*32, &Bs[cur^1][(r*256 + wid*64)*8]);
      }
    }
    bf16x8 a[2][2], bv[2][2];
    #pragma unroll
    for (int mf=0; mf<2; ++mf)
      #pragma unroll
      for (int s=0; s<2; ++s) a[mf][s] = *(const bf16x8*)&As[cur][abase + mf*512 + s*2048];
    #pragma unroll
    for (int nf=0; nf<2; ++nf)
      #pragma unroll
      for (int s=0; s<2; ++s) bv[nf][s] = *(const bf16x8*)&Bs[cur][bbase + nf*512 + s*2048];
    #pragma unroll
    for (int s=0; s<2; ++s)
      #pragma unroll
      for (int mf=0; mf<2; ++mf)
        #pragma unroll
        for (int nf=0; nf<2; ++nf)
          acc[mf][nf] = __builtin_amdgcn_mfma_f32_16x16x32_bf16(a[mf][s], bv[nf][s], acc[mf][nf], 0, 0, 0);
  }

  #pragma unroll
  for (int mf=0; mf<2; ++mf){
    int rowb = m0 + wr*32 + mf*16 + q*4;
    #pragma unroll
    for (int nf=0; nf<2; ++nf){
      f32x4 v = acc[mf][nf];
      int col = wc*32 + nf*16 + lr;
      #pragma unroll
      for (int j=0;j<4;++j) dbl[(size_t)(rowb+j)*GDBL + col] = v[j];
      if (wc == 0){
        #pragma unroll
        for (int j=0;j<4;++j) dtlob[(size_t)(rowb+j)*RDT + col] = f2bf(v[j]);
      }
    }
  }
}

// ---------------- K5: dt_proj bf16 MFMA GEMM + softplus -> dtb (B,L,E) bf16 ----------------
__global__ __launch_bounds__(256) void k5_dtproj_mfma(
    const u16* __restrict__ dtlob, const u16* __restrict__ wdtb,
    const float* __restrict__ dtbias, u16* __restrict__ dtb){
  __shared__ u16 As[2048];
  __shared__ u16 Bs[2048];
  int t = threadIdx.x;
  int wid = t >> 6, lane = t & 63;
  int m0 = blockIdx.x * 64, d0 = blockIdx.y * 64;
  int wr = wid >> 1, wc = wid & 1;
  int lr = lane & 15, q = lane >> 4;

  gld16(dtlob + (size_t)(m0 + (t>>2))*RDT + (t&3)*8, &As[wid*512]);
  gld16(wdtb  + (size_t)(d0 + (t>>2))*RDT + (t&3)*8, &Bs[wid*512]);
  __syncthreads();

  f32x4 acc[2][2];
  bf16x8 a[2], bv[2];
  #pragma unroll
  for (int mf=0; mf<2; ++mf) a[mf]  = *(const bf16x8*)&As[(wr*32 + mf*16 + lr)*32 + q*8];
  #pragma unroll
  for (int nf=0; nf<2; ++nf) bv[nf] = *(const bf16x8*)&Bs[(wc*32 + nf*16 + lr)*32 + q*8];
  #pragma unroll
  for (int mf=0; mf<2; ++mf)
    #pragma unroll
    for (int nf=0; nf<2; ++nf)
      acc[mf][nf] = __builtin_amdgcn_mfma_f32_16x16x32_bf16(a[mf], bv[nf], (f32x4){0.f,0.f,0.f,0.f}, 0, 0, 0);

  #pragma unroll
  for (int nf=0; nf<2; ++nf){
    int col = d0 + wc*32 + nf*16 + lr;
    float bias = dtbias[col];
    #pragma unroll
    for (int mf=0; mf<2; ++mf){
      int rowb = m0 + wr*32 + mf*16 + q*4;
      f32x4 v = acc[mf][nf];
      #pragma unroll
      for (int j=0;j<4;++j) dtb[(size_t)(rowb+j)*DINNER + col] = f2bf(softplusf(v[j] + bias));
    }
  }
}

// ---------------- K6a pass1: chunk summaries; 64d x 4ng threads, 4 h-states/thread ----------------
__global__ __launch_bounds__(256) void k6a_pass1(
    const float* __restrict__ dblg, const u16* __restrict__ xcg, const u16* __restrict__ dtg,
    const float* __restrict__ Alog,
    float* __restrict__ hend, float* __restrict__ dchunk){
  int blk = blockIdx.x;
  int b = blk >> 9;
  int dblk = (blk >> 5) & 15;
  int chunk = blk & 31;
  int d0 = dblk * 64;
  int t = threadIdx.x;
  int d = t >> 2, ng = t & 3;

  float4 Adn2;
  {
    float4 al = *(const float4*)&Alog[(d0+d)*NST + ng*4];
    Adn2.x = -__expf(al.x)*LOG2E; Adn2.y = -__expf(al.y)*LOG2E;
    Adn2.z = -__expf(al.z)*LOG2E; Adn2.w = -__expf(al.w)*LOG2E;
  }
  float h0=0.f, h1=0.f, h2=0.f, h3=0.f, S=0.f;

  __shared__ float dts[32][64];
  __shared__ float xcs[32][64];
  __shared__ float Bst[32][16];

  for (int sub = 0; sub < CHL/32; ++sub){
    int l0 = chunk*CHL + sub*32;
    __syncthreads();
    { // stage dt, xc (bf16x8), B
      int r = t >> 3, c8 = t & 7;
      size_t row = (size_t)(b*LSEQ + l0 + r);
      uint4 dv = *(const uint4*)&dtg[row*DINNER + d0 + c8*8];
      uint4 xv = *(const uint4*)&xcg[row*DINNER + d0 + c8*8];
      float df[8], xf[8];
      unpack8(dv, df); unpack8(xv, xf);
      *(float4*)&dts[r][c8*8]   = make_float4(df[0],df[1],df[2],df[3]);
      *(float4*)&dts[r][c8*8+4] = make_float4(df[4],df[5],df[6],df[7]);
      *(float4*)&xcs[r][c8*8]   = make_float4(xf[0],xf[1],xf[2],xf[3]);
      *(float4*)&xcs[r][c8*8+4] = make_float4(xf[4],xf[5],xf[6],xf[7]);
      if (t < 128){
        int rB = t >> 2, qB = t & 3;
        *(float4*)&Bst[rB][qB*4] = *(const float4*)&dblg[((size_t)(b*LSEQ + l0 + rB))*GDBL + RDT + qB*4];
      }
    }
    __syncthreads();
    #pragma unroll 4
    for (int r = 0; r < 32; ++r){
      float dtv = dts[r][d];
      float xcv = xcs[r][d];
      float4 Bv = *(const float4*)&Bst[r][ng*4];
      float u = dtv * xcv;
      h0 = exp2fast(dtv*Adn2.x)*h0 + u*Bv.x;
      h1 = exp2fast(dtv*Adn2.y)*h1 + u*Bv.y;
      h2 = exp2fast(dtv*Adn2.z)*h2 + u*Bv.z;
      h3 = exp2fast(dtv*Adn2.w)*h3 + u*Bv.w;
      S += dtv;
    }
  }
  size_t cix = ((size_t)(b*NCH + chunk)*DINNER + d0 + d)*NST + ng*4;
  *(float4*)&hend[cix]   = make_float4(h0, h1, h2, h3);
  *(float4*)&dchunk[cix] = make_float4(exp2fast(Adn2.x*S), exp2fast(Adn2.y*S),
                                       exp2fast(Adn2.z*S), exp2fast(Adn2.w*S));
}

// ---------------- K6c pass2: seeded scan; quad_perm n-reduce; gated bf16 y out ----------------
__global__ __launch_bounds__(256) void k6c_pass2(
    const float* __restrict__ dblg, const u16* __restrict__ xcg, const u16* __restrict__ zg,
    const u16* __restrict__ dtg,
    const float* __restrict__ Alog, const float* __restrict__ Dp,
    const float* __restrict__ hend, const float* __restrict__ dchk,
    u16* __restrict__ ybf){
  int blk = blockIdx.x;
  int b = blk >> 9;
  int dblk = (blk >> 5) & 15;
  int chunk = blk & 31;
  int d0 = dblk * 64;
  int t = threadIdx.x;
  int d = t >> 2, ng = t & 3;

  float4 Adn2;
  {
    float4 al = *(const float4*)&Alog[(d0+d)*NST + ng*4];
    Adn2.x = -__expf(al.x)*LOG2E; Adn2.y = -__expf(al.y)*LOG2E;
    Adn2.z = -__expf(al.z)*LOG2E; Adn2.w = -__expf(al.w)*LOG2E;
  }

  // inline h0: exclusive prefix over chunk summaries (float4 per step)
  float h0=0.f, h1=0.f, h2=0.f, h3=0.f;
  {
    size_t base = ((size_t)(b*NCH)*DINNER + d0 + d)*NST + ng*4;
    for (int c = 0; c < chunk; ++c){
      size_t ix = base + (size_t)c*DINNER*NST;
      float4 hv = *(const float4*)&hend[ix];
      float4 dv = *(const float4*)&dchk[ix];
      h0 = dv.x*h0 + hv.x; h1 = dv.y*h1 + hv.y;
      h2 = dv.z*h2 + hv.z; h3 = dv.w*h3 + hv.w;
    }
  }

  __shared__ float dts[32][64];
  __shared__ float xcs[32][64];
  __shared__ float BCs[32][32];   // B cols 0..15, C cols 16..31
  __shared__ float ys[32][64];
  __shared__ float Dps[64];

  if (t < 64) Dps[t] = Dp[d0 + t];

  for (int sub = 0; sub < CHL/32; ++sub){
    int l0 = chunk*CHL + sub*32;
    __syncthreads();
    { // stage dt, xc (bf16x8), B+C
      int r = t >> 3, c8 = t & 7;
      size_t row = (size_t)(b*LSEQ + l0 + r);
      uint4 dv = *(const uint4*)&dtg[row*DINNER + d0 + c8*8];
      uint4 xv = *(const uint4*)&xcg[row*DINNER + d0 + c8*8];
      float df[8], xf[8];
      unpack8(dv, df); unpack8(xv, xf);
      *(float4*)&dts[r][c8*8]   = make_float4(df[0],df[1],df[2],df[3]);
      *(float4*)&dts[r][c8*8+4] = make_float4(df[4],df[5],df[6],df[7]);
      *(float4*)&xcs[r][c8*8]   = make_float4(xf[0],xf[1],xf[2],xf[3]);
      *(float4*)&xcs[r][c8*8+4] = make_float4(xf[4],xf[5],xf[6],xf[7]);
      *(float4*)&BCs[r][c8*4]   = *(const float4*)&dblg[row*GDBL + RDT + c8*4];
    }
    __syncthreads();
    #pragma unroll 4
    for (int r = 0; r < 32; ++r){
      float dtv = dts[r][d];
      float xcv = xcs[r][d];
      float4 Bv = *(const float4*)&BCs[r][ng*4];
      float4 Cv = *(const float4*)&BCs[r][16 + ng*4];
      float u = dtv * xcv;
      h0 = exp2fast(dtv*Adn2.x)*h0 + u*Bv.x;
      h1 = exp2fast(dtv*Adn2.y)*h1 + u*Bv.y;
      h2 = exp2fast(dtv*Adn2.z)*h2 + u*Bv.z;
      h3 = exp2fast(dtv*Adn2.w)*h3 + u*Bv.w;
      float p = h0*Cv.x + h1*Cv.y + h2*Cv.z + h3*Cv.w;
      p = quadsum(p);
      if (ng == 0) ys[r][d] = p;
    }
    __syncthreads();
    { // gate + bf16 write (B,L,E)
      int r = t >> 3, c8 = t & 7;
      size_t row = (size_t)(b*LSEQ + l0 + r);
      uint4 zv = *(const uint4*)&zg[row*DINNER + d0 + c8*8];
      float zf[8]; unpack8(zv, zf);
      float4 s0 = *(const float4*)&ys[r][c8*8];
      float4 s1 = *(const float4*)&ys[r][c8*8+4];
      float4 x0 = *(const float4*)&xcs[r][c8*8];
      float4 x1 = *(const float4*)&xcs[r][c8*8+4];
      float4 D0 = *(const float4*)&Dps[c8*8];
      float4 D1 = *(const float4*)&Dps[c8*8+4];
      float y0 = (s0.x + x0.x*D0.x)*siluf(zf[0]);
      float y1 = (s0.y + x0.y*D0.y)*siluf(zf[1]);
      float y2 = (s0.z + x0.z*D0.z)*siluf(zf[2]);
      float y3 = (s0.w + x0.w*D0.w)*siluf(zf[3]);
      float y4 = (s1.x + x1.x*D1.x)*siluf(zf[4]);
      float y5 = (s1.y + x1.y*D1.y)*siluf(zf[5]);
      float y6 = (s1.z + x1.z*D1.z)*siluf(zf[6]);
      float y7 = (s1.w + x1.w*D1.w)*siluf(zf[7]);
      uint4 o;
      o.x = (u32)f2bf(y0) | ((u32)f2bf(y1) << 16);
      o.y = (u32)f2bf(y2) | ((u32)f2bf(y3) << 16);
      o.z = (u32)f2bf(y4) | ((u32)f2bf(y5) << 16);
      o.w = (u32)f2bf(y6) | ((u32)f2bf(y7) << 16);
      *(uint4*)&ybf[row*DINNER + d0 + c8*8] = o;
    }
  }
}

// ---------------- K7: out_proj bf16 MFMA GEMM, TRANSPOSED bf16 output (B,DMODEL,L) ----------------
__global__ __launch_bounds__(256) void k7_outproj_mfma(
    const u16* __restrict__ ybf, const u16* __restrict__ wopb, u16* __restrict__ xmTb){
  __shared__ u16 As[2][4096];
  __shared__ u16 Bs[2][4096];
  int t = threadIdx.x;
  int wid = t >> 6, lane = t & 63;
  int n0 = blockIdx.x * 64, m0 = blockIdx.y * 64;
  int b  = m0 >> 11;
  int l0 = m0 & (LSEQ-1);
  int wr = wid >> 1, wc = wid & 1;
  int lr = lane & 15, q = lane >> 4;

  const u16* gA = ybf  + (size_t)(m0 + (t>>2))*DINNER + (t&3)*8;
  const u16* gB = wopb + (size_t)(n0 + (t>>2))*DINNER + (t&3)*8;

  f32x4 acc[2][2];
  #pragma unroll
  for (int i=0;i<2;++i)
    #pragma unroll
    for (int j=0;j<2;++j) acc[i][j] = (f32x4){0.f,0.f,0.f,0.f};

  #pragma unroll
  for (int r=0;r<2;++r){
    gld16(gA + r*32, &As[0][(r*256 + wid*64)*8]);
    gld16(gB + r*32, &Bs[0][(r*256 + wid*64)*8]);
  }
  const int abase = (wr*32 + lr)*32 + q*8;
  const int bbase = (wc*32 + lr)*32 + q*8;

  for (int ks = 0; ks < 16; ++ks){
    int cur = ks & 1;
    __syncthreads();
    if (ks < 15){
      const u16* gA2 = gA + (ks+1)*64;
      const u16* gB2 = gB + (ks+1)*64;
      #pragma unroll
      for (int r=0;r<2;++r){
        gld16(gA2 + r*32, &As[cur^1][(r*256 + wid*64)*8]);
        gld16(gB2 + r*32, &Bs[cur^1][(r*256 + wid*64)*8]);
      }
    }
    bf16x8 a[2][2], bv[2][2];
    #pragma unroll
    for (int mf=0; mf<2; ++mf)
      #pragma unroll
      for (int s=0; s<2; ++s) a[mf][s] = *(const bf16x8*)&As[cur][abase + mf*512 + s*2048];
    #pragma unroll
    for (int nf=0; nf<2; ++nf)
      #pragma unroll
      for (int s=0; s<2; ++s) bv[nf][s] = *(const bf16x8*)&Bs[cur][bbase + nf*512 + s*2048];
    #pragma unroll
    for (int s=0; s<2; ++s)
      #pragma unroll
      for (int mf=0; mf<2; ++mf)
        #pragma unroll
        for (int nf=0; nf<2; ++nf)
          acc[mf][nf] = __builtin_amdgcn_mfma_f32_16x16x32_bf16(a[mf][s], bv[nf][s], acc[mf][nf], 0, 0, 0);
  }

  // transposed bf16 store: 4 acc elements = 4 consecutive l -> one uint2 (8B)
  #pragma unroll
  for (int mf=0; mf<2; ++mf){
    int lrow = l0 + wr*32 + mf*16 + q*4;
    #pragma unroll
    for (int nf=0; nf<2; ++nf){
      f32x4 v = acc[mf][nf];
      int col = n0 + wc*32 + nf*16 + lr;
      u32 lo = (u32)f2bf(v[0]) | ((u32)f2bf(v[1]) << 16);
      u32 hi = (u32)f2bf(v[2]) | ((u32)f2bf(v[3]) << 16);
      *(uint2*)&xmTb[((size_t)(b*DMODEL + col))*LSEQ + lrow] = make_uint2(lo, hi);
    }
  }
}

// ---------------- K8: fused LN2 (stats + apply), 16-l blocks ----------------
__global__ void k8_fused(const float* __restrict__ x, const u16* __restrict__ xmTb,
                         const float* __restrict__ w2, const float* __restrict__ b2,
                         float* __restrict__ out){
  int blk = blockIdx.x;
  int b = blk >> 7;
  int l0 = (blk & 127) * 16;
  int t = threadIdx.x;
  int lc = t & 15, dc = t >> 4;
  const float* xb = x    + (size_t)b*DMODEL*LSEQ + l0 + lc;
  const u16*   xt = xmTb + (size_t)b*DMODEL*LSEQ + l0 + lc;
  float s=0.f, q=0.f;
  for (int d = dc*32; d < dc*32+32; ++d){
    float v = xb[d*LSEQ] + bf2f(xt[d*LSEQ]);
    s += v; q += v*v;
  }
  __shared__ float ss[16][17], qq[16][17];
  __shared__ float muL[16], rsL[16];
  ss[dc][lc]=s; qq[dc][lc]=q;
  __syncthreads();
  if (t < 16){
    float S=0.f,Q=0.f;
    for (int i=0;i<16;++i){S+=ss[i][t];Q+=qq[i][t];}
    float m = S/DMODEL;
    muL[t]=m; rsL[t]=rsqrtf(Q/DMODEL - m*m + 1e-5f);
  }
  __syncthreads();
  float mu = muL[lc], rs = rsL[lc];
  float* ob = out + (size_t)b*DMODEL*LSEQ + l0 + lc;
  for (int d = dc*32; d < dc*32+32; ++d){
    float v = xb[d*LSEQ] + bf2f(xt[d*LSEQ]);
    ob[d*LSEQ] = (v - mu)*rs*w2[d] + b2[d];
  }
}

extern "C" void kernel_launch(void* const* d_in, const int* in_sizes, int n_in,
                              void* d_out, int out_size, void* d_ws, size_t ws_size,
                              hipStream_t stream) {
  const float* x      = (const float*)d_in[0];
  const float* n1w    = (const float*)d_in[1];
  const float* n1b    = (const float*)d_in[2];
  const float* n2w    = (const float*)d_in[3];
  const float* n2b    = (const float*)d_in[4];
  const float* Wip    = (const float*)d_in[5];
  const float* cw     = (const float*)d_in[6];
  const float* cb     = (const float*)d_in[7];
  const float* Wxp    = (const float*)d_in[8];
  const float* Wdt    = (const float*)d_in[9];
  const float* dtbias = (const float*)d_in[10];
  const float* Alog   = (const float*)d_in[11];
  const float* Dp     = (const float*)d_in[12];
  const float* Wop    = (const float*)d_in[13];
  float* out = (float*)d_out;

  // Workspace layout (float offsets), ~62 MB total
  float* ws = (float*)d_ws;
  size_t o = 0;
  u16*  xinb = (u16*)(ws + o); o += 2097152;   // (B,L,E) bf16
  u16*  zb   = (u16*)(ws + o); o += 2097152;   // (B,L,E) bf16
  u16*  xcb  = (u16*)(ws + o); o += 2097152;   // (B,L,E) bf16
  u16*  ybf  = (u16*)(ws + o); o += 2097152;   // (B,L,E) bf16
  u16*  dtb  = (u16*)(ws + o); o += 2097152;   // (B,L,E) bf16 dt
  u16*  xnb  = (u16*)(ws + o); o += 1048576;   // (B,L,D) bf16
  u16*  wipb = (u16*)(ws + o); o += 524288;    // (2048,512) bf16
  u16*  wopb = (u16*)(ws + o); o += 262144;    // (512,1024) bf16
  u16*  wxpb = (u16*)(ws + o); o += 32768;     // (64,1024) bf16
  u16*  wdtb = (u16*)(ws + o); o += 16384;     // (1024,32) bf16
  u16*  dtlob= (u16*)(ws + o); o += 65536;     // (B,L,32) bf16
  float* dbl  = ws + o; o += 262144;           // (B,L,64) fp32
  float* hend = ws + o; o += 1048576;          // (B,NCH,E,NST)
  float* dchk = ws + o; o += 1048576;
  u16*  xmTb  = (u16*)(ws + o); o += 1048576;  // (B,DMODEL,L) bf16

  k01_wcvt_ln  <<<dim3(1760),        dim3(256), 0, stream>>>(Wip, Wop, Wxp, Wdt, wipb, wopb, wxpb, wdtb,
                                                             x, n1w, n1b, xnb);
  k2_inproj_mfma<<<dim3(16,32),      dim3(256), 0, stream>>>(xnb, wipb, xinb, zb);
  k3_conv      <<<dim3(4096),        dim3(256), 0, stream>>>(xinb, cw, cb, xcb);
  k4_xproj_mfma<<<dim3(64),          dim3(256), 0, stream>>>(xcb, wxpb, dbl, dtlob);
  k5_dtproj_mfma<<<dim3(64,16),      dim3(256), 0, stream>>>(dtlob, wdtb, dtbias, dtb);
  k6a_pass1    <<<dim3(BSZ*16*NCH),  dim3(256), 0, stream>>>(dbl, xcb, dtb, Alog, hend, dchk);
  k6c_pass2    <<<dim3(BSZ*16*NCH),  dim3(256), 0, stream>>>(dbl, xcb, zb, dtb, Alog, Dp, hend, dchk, ybf);
  k7_outproj_mfma<<<dim3(8,64),      dim3(256), 0, stream>>>(ybf, wopb, xmTb);
  k8_fused     <<<dim3(BSZ*128),     dim3(256), 0, stream>>>(x, xmTb, n2w, n2b, out);
}

// Round 14
// 146.659 us; speedup vs baseline: 1.1101x; 1.0152x over previous
//
#include <hip/hip_runtime.h>
#include <math.h>

#define BSZ 2
#define LSEQ 2048
#define DMODEL 512
#define DINNER 1024
#define NST 16
#define RDT 32
#define GDBL 64   // RDT + 2*NST
#define NCH 32    // chunks over L
#define CHL 64    // steps per chunk
#define LOG2E 1.4426950408889634f
#define LN2   0.6931471805599453f

typedef unsigned short u16;
typedef unsigned int   u32;
typedef __attribute__((ext_vector_type(8))) __bf16 bf16x8;
typedef __attribute__((ext_vector_type(4))) float  f32x4;

__device__ __forceinline__ u16 f2bf(float f){
  u32 u = __float_as_uint(f);
  u += 0x7fff + ((u >> 16) & 1);
  return (u16)(u >> 16);
}
__device__ __forceinline__ float bf2f(u16 u){ return __uint_as_float((u32)u << 16); }
__device__ __forceinline__ float exp2fast(float x){
  float r; asm("v_exp_f32 %0, %1" : "=v"(r) : "v"(x)); return r;
}
__device__ __forceinline__ float log2fast(float x){
  float r; asm("v_log_f32 %0, %1" : "=v"(r) : "v"(x)); return r;
}
__device__ __forceinline__ float rcpfast(float x){
  float r; asm("v_rcp_f32 %0, %1" : "=v"(r) : "v"(x)); return r;
}
// silu(x) = x * rcp(1 + 2^(-x*log2e))
__device__ __forceinline__ float siluf(float x){
  return x * rcpfast(1.f + exp2fast(-x*LOG2E));
}
// softplus(x) = log2(1 + 2^(x*log2e)) * ln2
__device__ __forceinline__ float softplusf(float x){
  if (x > 20.f) return x;
  return log2fast(1.f + exp2fast(x*LOG2E)) * LN2;
}
// async global->LDS, 16B per lane
__device__ __forceinline__ void gld16(const void* g, void* l){
  __builtin_amdgcn_global_load_lds((const __attribute__((address_space(1))) void*)g,
                                   (__attribute__((address_space(3))) void*)l, 16, 0, 0);
}
// unpack 8 packed bf16 (uint4) -> 8 f32
__device__ __forceinline__ void unpack8(uint4 v, float* f){
  f[0]=__uint_as_float(v.x<<16); f[1]=__uint_as_float(v.x&0xffff0000u);
  f[2]=__uint_as_float(v.y<<16); f[3]=__uint_as_float(v.y&0xffff0000u);
  f[4]=__uint_as_float(v.z<<16); f[5]=__uint_as_float(v.z&0xffff0000u);
  f[6]=__uint_as_float(v.w<<16); f[7]=__uint_as_float(v.w&0xffff0000u);
}
// sum across the 4 lanes of a quad: 2 DPP quad_perm adds
__device__ __forceinline__ float quadsum(float p){
  p += __int_as_float(__builtin_amdgcn_update_dpp(0, __float_as_int(p), 0xB1, 0xf, 0xf, true)); // [1,0,3,2]
  p += __int_as_float(__builtin_amdgcn_update_dpp(0, __float_as_int(p), 0x4E, 0xf, 0xf, true)); // [2,3,0,1]
  return p;
}

// ---------------- K01: weight cvt (blocks 0..1631) + LN1 norm (blocks 1632..1759) ----------------
__global__ void k01_wcvt_ln(const float* __restrict__ Wip, const float* __restrict__ Wop,
                            const float* __restrict__ Wxp, const float* __restrict__ Wdt,
                            u16* __restrict__ wipb, u16* __restrict__ wopb,
                            u16* __restrict__ wxpb, u16* __restrict__ wdtb,
                            const float* __restrict__ x, const float* __restrict__ w1,
                            const float* __restrict__ b1, u16* __restrict__ xnb){
  __shared__ float ss[8][33], qq[8][33];
  __shared__ float muL[32], rsL[32];
  if (blockIdx.x < 1632){
    int idx = blockIdx.x*256 + threadIdx.x;
    int i4 = idx * 4;
    const float* src; u16* dst;
    if (i4 < 1048576){ src = Wip + i4; dst = wipb + i4; }
    else if (i4 < 1048576 + 524288){ int j = i4 - 1048576; src = Wop + j; dst = wopb + j; }
    else if (i4 < 1048576 + 524288 + 65536){ int j = i4 - 1048576 - 524288; src = Wxp + j; dst = wxpb + j; }
    else { int j = i4 - 1048576 - 524288 - 65536; if (j >= 32768) return; src = Wdt + j; dst = wdtb + j; }
    float4 v = *(const float4*)src;
    u32 lo = (u32)f2bf(v.x) | ((u32)f2bf(v.y) << 16);
    u32 hi = (u32)f2bf(v.z) | ((u32)f2bf(v.w) << 16);
    *(uint2*)dst = make_uint2(lo, hi);
    return;
  }
  // LN1: 128 blocks of 32 l; 32 lc x 8 dc (64 d each)
  int blk = blockIdx.x - 1632;
  int b = blk >> 6;
  int l0 = (blk & 63) * 32;
  int t = threadIdx.x;
  int lc = t & 31, dc = t >> 5;
  const float* xb = x + (size_t)b*DMODEL*LSEQ;
  float s=0.f, q=0.f;
  for (int d = dc*64; d < dc*64+64; ++d){
    float v = xb[d*LSEQ + l0 + lc];
    s += v; q += v*v;
  }
  ss[dc][lc]=s; qq[dc][lc]=q;
  __syncthreads();
  if (t < 32){
    float S=0.f,Q=0.f;
    for (int i=0;i<8;++i){S+=ss[i][t];Q+=qq[i][t];}
    float m = S/DMODEL;
    muL[t]=m; rsL[t]=rsqrtf(Q/DMODEL - m*m + 1e-5f);
  }
  __syncthreads();
  float mu = muL[lc], rs = rsL[lc];
  u16* orow = xnb + ((size_t)(b*LSEQ + l0 + lc))*DMODEL;
  for (int d = dc*64; d < dc*64+64; d += 2){
    float v0 = (xb[d*LSEQ + l0 + lc]     - mu)*rs*w1[d]   + b1[d];
    float v1 = (xb[(d+1)*LSEQ + l0 + lc] - mu)*rs*w1[d+1] + b1[d+1];
    *(u32*)&orow[d] = (u32)f2bf(v0) | ((u32)f2bf(v1) << 16);
  }
}

// ---------------- K2: in_proj bf16 MFMA GEMM, BK=64 (8 K-steps) ----------------
__global__ __launch_bounds__(256) void k2_inproj_mfma(
    const u16* __restrict__ xnb, const u16* __restrict__ wipb,
    u16* __restrict__ xinb, u16* __restrict__ zb){
  __shared__ u16 As[2][8192];   // 128 rows x 64 k
  __shared__ u16 Bs[2][8192];
  int t = threadIdx.x;
  int wid = t >> 6, lane = t & 63;
  int n0 = blockIdx.x * 128, m0 = blockIdx.y * 128;
  int wr = wid >> 1, wc = wid & 1;
  int lr = lane & 15, q = lane >> 4;

  const u16* gA = xnb  + (size_t)(m0 + (t>>3))*DMODEL + (t&7)*8;
  const u16* gB = wipb + (size_t)(n0 + (t>>3))*DMODEL + (t&7)*8;

  f32x4 acc[4][4];
  #pragma unroll
  for (int i=0;i<4;++i)
    #pragma unroll
    for (int j=0;j<4;++j) acc[i][j] = (f32x4){0.f,0.f,0.f,0.f};

  #pragma unroll
  for (int r=0;r<4;++r){
    gld16(gA + (size_t)r*32*DMODEL, &As[0][r*2048 + wid*512]);
    gld16(gB + (size_t)r*32*DMODEL, &Bs[0][r*2048 + wid*512]);
  }
  const int abase = (wr*64 + lr)*64 + q*8;
  const int bbase = (wc*64 + lr)*64 + q*8;

  for (int ks = 0; ks < 8; ++ks){
    int cur = ks & 1;
    __syncthreads();
    if (ks < 7){
      const u16* gA2 = gA + (ks+1)*64;
      const u16* gB2 = gB + (ks+1)*64;
      #pragma unroll
      for (int r=0;r<4;++r){
        gld16(gA2 + (size_t)r*32*DMODEL, &As[cur^1][r*2048 + wid*512]);
        gld16(gB2 + (size_t)r*32*DMODEL, &Bs[cur^1][r*2048 + wid*512]);
      }
    }
    bf16x8 a[4][2], bv[4][2];
    #pragma unroll
    for (int mf=0; mf<4; ++mf)
      #pragma unroll
      for (int s=0; s<2; ++s) a[mf][s] = *(const bf16x8*)&As[cur][abase + mf*1024 + s*32];
    #pragma unroll
    for (int nf=0; nf<4; ++nf)
      #pragma unroll
      for (int s=0; s<2; ++s) bv[nf][s] = *(const bf16x8*)&Bs[cur][bbase + nf*1024 + s*32];
    #pragma unroll
    for (int s=0; s<2; ++s)
      #pragma unroll
      for (int mf=0; mf<4; ++mf)
        #pragma unroll
        for (int nf=0; nf<4; ++nf)
          acc[mf][nf] = __builtin_amdgcn_mfma_f32_16x16x32_bf16(a[mf][s], bv[nf][s], acc[mf][nf], 0, 0, 0);
  }

  bool half = (n0 >= DINNER);
  u16* outp = half ? zb : xinb;
  int colb = (half ? n0 - DINNER : n0) + wc*64 + lr;
  #pragma unroll
  for (int mf=0; mf<4; ++mf){
    int rowb = m0 + wr*64 + mf*16 + q*4;
    #pragma unroll
    for (int nf=0; nf<4; ++nf){
      f32x4 v = acc[mf][nf];
      int col = colb + nf*16;
      #pragma unroll
      for (int j=0;j<4;++j) outp[(size_t)(rowb+j)*DINNER + col] = f2bf(v[j]);
    }
  }
}

// ---------------- K3: causal depthwise conv (K=4) + SiLU, bf16 in -> bf16 out ----------------
__global__ void k3_conv(const u16* __restrict__ xinb, const float* __restrict__ cw,
                        const float* __restrict__ cb, u16* __restrict__ xc){
  int idx = blockIdx.x*blockDim.x + threadIdx.x;
  int e4 = (idx & (DINNER/4 - 1)) * 4;
  int m = idx >> 8;
  int b = m >> 11; int l = m & (LSEQ-1);
  float4 accb = *(const float4*)&cb[e4];
  float acc[4] = {accb.x, accb.y, accb.z, accb.w};
  #pragma unroll
  for (int k=0;k<4;++k){
    int li = l + k - 3;
    if (li >= 0){
      ushort4 v = *(const ushort4*)&xinb[((size_t)(b*LSEQ+li))*DINNER + e4];
      acc[0] += bf2f(v.x) * cw[(e4+0)*4 + k];
      acc[1] += bf2f(v.y) * cw[(e4+1)*4 + k];
      acc[2] += bf2f(v.z) * cw[(e4+2)*4 + k];
      acc[3] += bf2f(v.w) * cw[(e4+3)*4 + k];
    }
  }
  u32 lo = (u32)f2bf(siluf(acc[0])) | ((u32)f2bf(siluf(acc[1])) << 16);
  u32 hi = (u32)f2bf(siluf(acc[2])) | ((u32)f2bf(siluf(acc[3])) << 16);
  *(uint2*)&xc[(size_t)m*DINNER + e4] = make_uint2(lo, hi);
}

// ---------------- K4: x_proj bf16 MFMA GEMM, BK=128 (8 K-steps); +bf16 dt_lo side out ----------------
__global__ __launch_bounds__(256) void k4_xproj_mfma(
    const u16* __restrict__ xcbf, const u16* __restrict__ wxpb,
    float* __restrict__ dbl, u16* __restrict__ dtlob){
  __shared__ u16 As[2][8192];   // [s<4][64 rows][32 k]
  __shared__ u16 Bs[2][8192];
  int t = threadIdx.x;
  int wid = t >> 6, lane = t & 63;
  int m0 = blockIdx.x * 64;
  int wr = wid >> 1, wc = wid & 1;
  int lr = lane & 15, q = lane >> 4;

  const u16* gA = xcbf + (size_t)(m0 + (t>>2))*DINNER + (t&3)*8;
  const u16* gB = wxpb + (size_t)(t>>2)*DINNER + (t&3)*8;

  f32x4 acc[2][2];
  #pragma unroll
  for (int i=0;i<2;++i)
    #pragma unroll
    for (int j=0;j<2;++j) acc[i][j] = (f32x4){0.f,0.f,0.f,0.f};

  #pragma unroll
  for (int s=0;s<4;++s){
    gld16(gA + s*32, &As[0][s*2048 + wid*512]);
    gld16(gB + s*32, &Bs[0][s*2048 + wid*512]);
  }
  const int abase = (wr*32 + lr)*32 + q*8;
  const int bbase = (wc*32 + lr)*32 + q*8;

  for (int ks = 0; ks < 8; ++ks){
    int cur = ks & 1;
    __syncthreads();
    if (ks < 7){
      const u16* gA2 = gA + (ks+1)*128;
      const u16* gB2 = gB + (ks+1)*128;
      #pragma unroll
      for (int s=0;s<4;++s){
        gld16(gA2 + s*32, &As[cur^1][s*2048 + wid*512]);
        gld16(gB2 + s*32, &Bs[cur^1][s*2048 + wid*512]);
      }
    }
    bf16x8 a[2][4], bv[2][4];
    #pragma unroll
    for (int mf=0; mf<2; ++mf)
      #pragma unroll
      for (int s=0; s<4; ++s) a[mf][s] = *(const bf16x8*)&As[cur][abase + mf*512 + s*2048];
    #pragma unroll
    for (int nf=0; nf<2; ++nf)
      #pragma unroll
      for (int s=0; s<4; ++s) bv[nf][s] = *(const bf16x8*)&Bs[cur][bbase + nf*512 + s*2048];
    #pragma unroll
    for (int s=0; s<4; ++s)
      #pragma unroll
      for (int mf=0; mf<2; ++mf)
        #pragma unroll
        for (int nf=0; nf<2; ++nf)
          acc[mf][nf] = __builtin_amdgcn_mfma_f32_16x16x32_bf16(a[mf][s], bv[nf][s], acc[mf][nf], 0, 0, 0);
  }

  #pragma unroll
  for (int mf=0; mf<2; ++mf){
    int rowb = m0 + wr*32 + mf*16 + q*4;
    #pragma unroll
    for (int nf=0; nf<2; ++nf){
      f32x4 v = acc[mf][nf];
      int col = wc*32 + nf*16 + lr;
      #pragma unroll
      for (int j=0;j<4;++j) dbl[(size_t)(rowb+j)*GDBL + col] = v[j];
      if (wc == 0){
        #pragma unroll
        for (int j=0;j<4;++j) dtlob[(size_t)(rowb+j)*RDT + col] = f2bf(v[j]);
      }
    }
  }
}

// ---------------- K5: dt_proj bf16 MFMA GEMM + softplus -> dtb (B,L,E) bf16 ----------------
__global__ __launch_bounds__(256) void k5_dtproj_mfma(
    const u16* __restrict__ dtlob, const u16* __restrict__ wdtb,
    const float* __restrict__ dtbias, u16* __restrict__ dtb){
  __shared__ u16 As[2048];
  __shared__ u16 Bs[2048];
  int t = threadIdx.x;
  int wid = t >> 6, lane = t & 63;
  int m0 = blockIdx.x * 64, d0 = blockIdx.y * 64;
  int wr = wid >> 1, wc = wid & 1;
  int lr = lane & 15, q = lane >> 4;

  gld16(dtlob + (size_t)(m0 + (t>>2))*RDT + (t&3)*8, &As[wid*512]);
  gld16(wdtb  + (size_t)(d0 + (t>>2))*RDT + (t&3)*8, &Bs[wid*512]);
  __syncthreads();

  f32x4 acc[2][2];
  bf16x8 a[2], bv[2];
  #pragma unroll
  for (int mf=0; mf<2; ++mf) a[mf]  = *(const bf16x8*)&As[(wr*32 + mf*16 + lr)*32 + q*8];
  #pragma unroll
  for (int nf=0; nf<2; ++nf) bv[nf] = *(const bf16x8*)&Bs[(wc*32 + nf*16 + lr)*32 + q*8];
  #pragma unroll
  for (int mf=0; mf<2; ++mf)
    #pragma unroll
    for (int nf=0; nf<2; ++nf)
      acc[mf][nf] = __builtin_amdgcn_mfma_f32_16x16x32_bf16(a[mf], bv[nf], (f32x4){0.f,0.f,0.f,0.f}, 0, 0, 0);

  #pragma unroll
  for (int nf=0; nf<2; ++nf){
    int col = d0 + wc*32 + nf*16 + lr;
    float bias = dtbias[col];
    #pragma unroll
    for (int mf=0; mf<2; ++mf){
      int rowb = m0 + wr*32 + mf*16 + q*4;
      f32x4 v = acc[mf][nf];
      #pragma unroll
      for (int j=0;j<4;++j) dtb[(size_t)(rowb+j)*DINNER + col] = f2bf(softplusf(v[j] + bias));
    }
  }
}

// ---------------- K6a pass1: chunk summaries; 64d x 4ng threads, 4 h-states/thread ----------------
__global__ __launch_bounds__(256) void k6a_pass1(
    const float* __restrict__ dblg, const u16* __restrict__ xcg, const u16* __restrict__ dtg,
    const float* __restrict__ Alog,
    float* __restrict__ hend, float* __restrict__ dchunk){
  int blk = blockIdx.x;
  int b = blk >> 9;
  int dblk = (blk >> 5) & 15;
  int chunk = blk & 31;
  int d0 = dblk * 64;
  int t = threadIdx.x;
  int d = t >> 2, ng = t & 3;

  float4 Adn2;
  {
    float4 al = *(const float4*)&Alog[(d0+d)*NST + ng*4];
    Adn2.x = -__expf(al.x)*LOG2E; Adn2.y = -__expf(al.y)*LOG2E;
    Adn2.z = -__expf(al.z)*LOG2E; Adn2.w = -__expf(al.w)*LOG2E;
  }
  float h0=0.f, h1=0.f, h2=0.f, h3=0.f, S=0.f;

  __shared__ float dts[32][64];
  __shared__ float xcs[32][64];
  __shared__ float Bst[32][16];

  for (int sub = 0; sub < CHL/32; ++sub){
    int l0 = chunk*CHL + sub*32;
    __syncthreads();
    { // stage dt, xc (bf16x8), B
      int r = t >> 3, c8 = t & 7;
      size_t row = (size_t)(b*LSEQ + l0 + r);
      uint4 dv = *(const uint4*)&dtg[row*DINNER + d0 + c8*8];
      uint4 xv = *(const uint4*)&xcg[row*DINNER + d0 + c8*8];
      float df[8], xf[8];
      unpack8(dv, df); unpack8(xv, xf);
      *(float4*)&dts[r][c8*8]   = make_float4(df[0],df[1],df[2],df[3]);
      *(float4*)&dts[r][c8*8+4] = make_float4(df[4],df[5],df[6],df[7]);
      *(float4*)&xcs[r][c8*8]   = make_float4(xf[0],xf[1],xf[2],xf[3]);
      *(float4*)&xcs[r][c8*8+4] = make_float4(xf[4],xf[5],xf[6],xf[7]);
      if (t < 128){
        int rB = t >> 2, qB = t & 3;
        *(float4*)&Bst[rB][qB*4] = *(const float4*)&dblg[((size_t)(b*LSEQ + l0 + rB))*GDBL + RDT + qB*4];
      }
    }
    __syncthreads();
    #pragma unroll 4
    for (int r = 0; r < 32; ++r){
      float dtv = dts[r][d];
      float xcv = xcs[r][d];
      float4 Bv = *(const float4*)&Bst[r][ng*4];
      float u = dtv * xcv;
      h0 = exp2fast(dtv*Adn2.x)*h0 + u*Bv.x;
      h1 = exp2fast(dtv*Adn2.y)*h1 + u*Bv.y;
      h2 = exp2fast(dtv*Adn2.z)*h2 + u*Bv.z;
      h3 = exp2fast(dtv*Adn2.w)*h3 + u*Bv.w;
      S += dtv;
    }
  }
  size_t cix = ((size_t)(b*NCH + chunk)*DINNER + d0 + d)*NST + ng*4;
  *(float4*)&hend[cix]   = make_float4(h0, h1, h2, h3);
  *(float4*)&dchunk[cix] = make_float4(exp2fast(Adn2.x*S), exp2fast(Adn2.y*S),
                                       exp2fast(Adn2.z*S), exp2fast(Adn2.w*S));
}

// ---------------- K6c pass2: seeded scan; quad_perm n-reduce; gated bf16 y out ----------------
__global__ __launch_bounds__(256) void k6c_pass2(
    const float* __restrict__ dblg, const u16* __restrict__ xcg, const u16* __restrict__ zg,
    const u16* __restrict__ dtg,
    const float* __restrict__ Alog, const float* __restrict__ Dp,
    const float* __restrict__ hend, const float* __restrict__ dchk,
    u16* __restrict__ ybf){
  int blk = blockIdx.x;
  int b = blk >> 9;
  int dblk = (blk >> 5) & 15;
  int chunk = blk & 31;
  int d0 = dblk * 64;
  int t = threadIdx.x;
  int d = t >> 2, ng = t & 3;

  float4 Adn2;
  {
    float4 al = *(const float4*)&Alog[(d0+d)*NST + ng*4];
    Adn2.x = -__expf(al.x)*LOG2E; Adn2.y = -__expf(al.y)*LOG2E;
    Adn2.z = -__expf(al.z)*LOG2E; Adn2.w = -__expf(al.w)*LOG2E;
  }

  // inline h0: exclusive prefix over chunk summaries (float4 per step)
  float h0=0.f, h1=0.f, h2=0.f, h3=0.f;
  {
    size_t base = ((size_t)(b*NCH)*DINNER + d0 + d)*NST + ng*4;
    for (int c = 0; c < chunk; ++c){
      size_t ix = base + (size_t)c*DINNER*NST;
      float4 hv = *(const float4*)&hend[ix];
      float4 dv = *(const float4*)&dchk[ix];
      h0 = dv.x*h0 + hv.x; h1 = dv.y*h1 + hv.y;
      h2 = dv.z*h2 + hv.z; h3 = dv.w*h3 + hv.w;
    }
  }

  __shared__ float dts[32][64];
  __shared__ float xcs[32][64];
  __shared__ float BCs[32][32];   // B cols 0..15, C cols 16..31
  __shared__ float ys[32][64];
  __shared__ float Dps[64];

  if (t < 64) Dps[t] = Dp[d0 + t];

  for (int sub = 0; sub < CHL/32; ++sub){
    int l0 = chunk*CHL + sub*32;
    __syncthreads();
    { // stage dt, xc (bf16x8), B+C
      int r = t >> 3, c8 = t & 7;
      size_t row = (size_t)(b*LSEQ + l0 + r);
      uint4 dv = *(const uint4*)&dtg[row*DINNER + d0 + c8*8];
      uint4 xv = *(const uint4*)&xcg[row*DINNER + d0 + c8*8];
      float df[8], xf[8];
      unpack8(dv, df); unpack8(xv, xf);
      *(float4*)&dts[r][c8*8]   = make_float4(df[0],df[1],df[2],df[3]);
      *(float4*)&dts[r][c8*8+4] = make_float4(df[4],df[5],df[6],df[7]);
      *(float4*)&xcs[r][c8*8]   = make_float4(xf[0],xf[1],xf[2],xf[3]);
      *(float4*)&xcs[r][c8*8+4] = make_float4(xf[4],xf[5],xf[6],xf[7]);
      *(float4*)&BCs[r][c8*4]   = *(const float4*)&dblg[row*GDBL + RDT + c8*4];
    }
    __syncthreads();
    #pragma unroll 4
    for (int r = 0; r < 32; ++r){
      float dtv = dts[r][d];
      float xcv = xcs[r][d];
      float4 Bv = *(const float4*)&BCs[r][ng*4];
      float4 Cv = *(const float4*)&BCs[r][16 + ng*4];
      float u = dtv * xcv;
      h0 = exp2fast(dtv*Adn2.x)*h0 + u*Bv.x;
      h1 = exp2fast(dtv*Adn2.y)*h1 + u*Bv.y;
      h2 = exp2fast(dtv*Adn2.z)*h2 + u*Bv.z;
      h3 = exp2fast(dtv*Adn2.w)*h3 + u*Bv.w;
      float p = h0*Cv.x + h1*Cv.y + h2*Cv.z + h3*Cv.w;
      p = quadsum(p);
      if (ng == 0) ys[r][d] = p;
    }
    __syncthreads();
    { // gate + bf16 write (B,L,E)
      int r = t >> 3, c8 = t & 7;
      size_t row = (size_t)(b*LSEQ + l0 + r);
      uint4 zv = *(const uint4*)&zg[row*DINNER + d0 + c8*8];
      float zf[8]; unpack8(zv, zf);
      float4 s0 = *(const float4*)&ys[r][c8*8];
      float4 s1 = *(const float4*)&ys[r][c8*8+4];
      float4 x0 = *(const float4*)&xcs[r][c8*8];
      float4 x1 = *(const float4*)&xcs[r][c8*8+4];
      float4 D0 = *(const float4*)&Dps[c8*8];
      float4 D1 = *(const float4*)&Dps[c8*8+4];
      float y0 = (s0.x + x0.x*D0.x)*siluf(zf[0]);
      float y1 = (s0.y + x0.y*D0.y)*siluf(zf[1]);
      float y2 = (s0.z + x0.z*D0.z)*siluf(zf[2]);
      float y3 = (s0.w + x0.w*D0.w)*siluf(zf[3]);
      float y4 = (s1.x + x1.x*D1.x)*siluf(zf[4]);
      float y5 = (s1.y + x1.y*D1.y)*siluf(zf[5]);
      float y6 = (s1.z + x1.z*D1.z)*siluf(zf[6]);
      float y7 = (s1.w + x1.w*D1.w)*siluf(zf[7]);
      uint4 o;
      o.x = (u32)f2bf(y0) | ((u32)f2bf(y1) << 16);
      o.y = (u32)f2bf(y2) | ((u32)f2bf(y3) << 16);
      o.z = (u32)f2bf(y4) | ((u32)f2bf(y5) << 16);
      o.w = (u32)f2bf(y6) | ((u32)f2bf(y7) << 16);
      *(uint4*)&ybf[row*DINNER + d0 + c8*8] = o;
    }
  }
}

// ---------------- K7: out_proj bf16 MFMA GEMM, BK=128 (8 K-steps), bf16 transposed out ----------------
__global__ __launch_bounds__(256) void k7_outproj_mfma(
    const u16* __restrict__ ybf, const u16* __restrict__ wopb, u16* __restrict__ xmTb){
  __shared__ u16 As[2][8192];   // [s<4][64 rows][32 k]
  __shared__ u16 Bs[2][8192];
  int t = threadIdx.x;
  int wid = t >> 6, lane = t & 63;
  int n0 = blockIdx.x * 64, m0 = blockIdx.y * 64;
  int b  = m0 >> 11;
  int l0 = m0 & (LSEQ-1);
  int wr = wid >> 1, wc = wid & 1;
  int lr = lane & 15, q = lane >> 4;

  const u16* gA = ybf  + (size_t)(m0 + (t>>2))*DINNER + (t&3)*8;
  const u16* gB = wopb + (size_t)(n0 + (t>>2))*DINNER + (t&3)*8;

  f32x4 acc[2][2];
  #pragma unroll
  for (int i=0;i<2;++i)
    #pragma unroll
    for (int j=0;j<2;++j) acc[i][j] = (f32x4){0.f,0.f,0.f,0.f};

  #pragma unroll
  for (int s=0;s<4;++s){
    gld16(gA + s*32, &As[0][s*2048 + wid*512]);
    gld16(gB + s*32, &Bs[0][s*2048 + wid*512]);
  }
  const int abase = (wr*32 + lr)*32 + q*8;
  const int bbase = (wc*32 + lr)*32 + q*8;

  for (int ks = 0; ks < 8; ++ks){
    int cur = ks & 1;
    __syncthreads();
    if (ks < 7){
      const u16* gA2 = gA + (ks+1)*128;
      const u16* gB2 = gB + (ks+1)*128;
      #pragma unroll
      for (int s=0;s<4;++s){
        gld16(gA2 + s*32, &As[cur^1][s*2048 + wid*512]);
        gld16(gB2 + s*32, &Bs[cur^1][s*2048 + wid*512]);
      }
    }
    bf16x8 a[2][4], bv[2][4];
    #pragma unroll
    for (int mf=0; mf<2; ++mf)
      #pragma unroll
      for (int s=0; s<4; ++s) a[mf][s] = *(const bf16x8*)&As[cur][abase + mf*512 + s*2048];
    #pragma unroll
    for (int nf=0; nf<2; ++nf)
      #pragma unroll
      for (int s=0; s<4; ++s) bv[nf][s] = *(const bf16x8*)&Bs[cur][bbase + nf*512 + s*2048];
    #pragma unroll
    for (int s=0; s<4; ++s)
      #pragma unroll
      for (int mf=0; mf<2; ++mf)
        #pragma unroll
        for (int nf=0; nf<2; ++nf)
          acc[mf][nf] = __builtin_amdgcn_mfma_f32_16x16x32_bf16(a[mf][s], bv[nf][s], acc[mf][nf], 0, 0, 0);
  }

  // transposed bf16 store: 4 acc elements = 4 consecutive l -> one uint2 (8B)
  #pragma unroll
  for (int mf=0; mf<2; ++mf){
    int lrow = l0 + wr*32 + mf*16 + q*4;
    #pragma unroll
    for (int nf=0; nf<2; ++nf){
      f32x4 v = acc[mf][nf];
      int col = n0 + wc*32 + nf*16 + lr;
      u32 lo = (u32)f2bf(v[0]) | ((u32)f2bf(v[1]) << 16);
      u32 hi = (u32)f2bf(v[2]) | ((u32)f2bf(v[3]) << 16);
      *(uint2*)&xmTb[((size_t)(b*DMODEL + col))*LSEQ + lrow] = make_uint2(lo, hi);
    }
  }
}

// ---------------- K8: fused LN2 (stats + apply), 16-l blocks ----------------
__global__ void k8_fused(const float* __restrict__ x, const u16* __restrict__ xmTb,
                         const float* __restrict__ w2, const float* __restrict__ b2,
                         float* __restrict__ out){
  int blk = blockIdx.x;
  int b = blk >> 7;
  int l0 = (blk & 127) * 16;
  int t = threadIdx.x;
  int lc = t & 15, dc = t >> 4;
  const float* xb = x    + (size_t)b*DMODEL*LSEQ + l0 + lc;
  const u16*   xt = xmTb + (size_t)b*DMODEL*LSEQ + l0 + lc;
  float s=0.f, q=0.f;
  for (int d = dc*32; d < dc*32+32; ++d){
    float v = xb[d*LSEQ] + bf2f(xt[d*LSEQ]);
    s += v; q += v*v;
  }
  __shared__ float ss[16][17], qq[16][17];
  __shared__ float muL[16], rsL[16];
  ss[dc][lc]=s; qq[dc][lc]=q;
  __syncthreads();
  if (t < 16){
    float S=0.f,Q=0.f;
    for (int i=0;i<16;++i){S+=ss[i][t];Q+=qq[i][t];}
    float m = S/DMODEL;
    muL[t]=m; rsL[t]=rsqrtf(Q/DMODEL - m*m + 1e-5f);
  }
  __syncthreads();
  float mu = muL[lc], rs = rsL[lc];
  float* ob = out + (size_t)b*DMODEL*LSEQ + l0 + lc;
  for (int d = dc*32; d < dc*32+32; ++d){
    float v = xb[d*LSEQ] + bf2f(xt[d*LSEQ]);
    ob[d*LSEQ] = (v - mu)*rs*w2[d] + b2[d];
  }
}

extern "C" void kernel_launch(void* const* d_in, const int* in_sizes, int n_in,
                              void* d_out, int out_size, void* d_ws, size_t ws_size,
                              hipStream_t stream) {
  const float* x      = (const float*)d_in[0];
  const float* n1w    = (const float*)d_in[1];
  const float* n1b    = (const float*)d_in[2];
  const float* n2w    = (const float*)d_in[3];
  const float* n2b    = (const float*)d_in[4];
  const float* Wip    = (const float*)d_in[5];
  const float* cw     = (const float*)d_in[6];
  const float* cb     = (const float*)d_in[7];
  const float* Wxp    = (const float*)d_in[8];
  const float* Wdt    = (const float*)d_in[9];
  const float* dtbias = (const float*)d_in[10];
  const float* Alog   = (const float*)d_in[11];
  const float* Dp     = (const float*)d_in[12];
  const float* Wop    = (const float*)d_in[13];
  float* out = (float*)d_out;

  // Workspace layout (float offsets), ~62 MB total
  float* ws = (float*)d_ws;
  size_t o = 0;
  u16*  xinb = (u16*)(ws + o); o += 2097152;   // (B,L,E) bf16
  u16*  zb   = (u16*)(ws + o); o += 2097152;   // (B,L,E) bf16
  u16*  xcb  = (u16*)(ws + o); o += 2097152;   // (B,L,E) bf16
  u16*  ybf  = (u16*)(ws + o); o += 2097152;   // (B,L,E) bf16
  u16*  dtb  = (u16*)(ws + o); o += 2097152;   // (B,L,E) bf16 dt
  u16*  xnb  = (u16*)(ws + o); o += 1048576;   // (B,L,D) bf16
  u16*  wipb = (u16*)(ws + o); o += 524288;    // (2048,512) bf16
  u16*  wopb = (u16*)(ws + o); o += 262144;    // (512,1024) bf16
  u16*  wxpb = (u16*)(ws + o); o += 32768;     // (64,1024) bf16
  u16*  wdtb = (u16*)(ws + o); o += 16384;     // (1024,32) bf16
  u16*  dtlob= (u16*)(ws + o); o += 65536;     // (B,L,32) bf16
  float* dbl  = ws + o; o += 262144;           // (B,L,64) fp32
  float* hend = ws + o; o += 1048576;          // (B,NCH,E,NST)
  float* dchk = ws + o; o += 1048576;
  u16*  xmTb  = (u16*)(ws + o); o += 1048576;  // (B,DMODEL,L) bf16

  k01_wcvt_ln  <<<dim3(1760),        dim3(256), 0, stream>>>(Wip, Wop, Wxp, Wdt, wipb, wopb, wxpb, wdtb,
                                                             x, n1w, n1b, xnb);
  k2_inproj_mfma<<<dim3(16,32),      dim3(256), 0, stream>>>(xnb, wipb, xinb, zb);
  k3_conv      <<<dim3(4096),        dim3(256), 0, stream>>>(xinb, cw, cb, xcb);
  k4_xproj_mfma<<<dim3(64),          dim3(256), 0, stream>>>(xcb, wxpb, dbl, dtlob);
  k5_dtproj_mfma<<<dim3(64,16),      dim3(256), 0, stream>>>(dtlob, wdtb, dtbias, dtb);
  k6a_pass1    <<<dim3(BSZ*16*NCH),  dim3(256), 0, stream>>>(dbl, xcb, dtb, Alog, hend, dchk);
  k6c_pass2    <<<dim3(BSZ*16*NCH),  dim3(256), 0, stream>>>(dbl, xcb, zb, dtb, Alog, Dp, hend, dchk, ybf);
  k7_outproj_mfma<<<dim3(8,64),      dim3(256), 0, stream>>>(ybf, wopb, xmTb);
  k8_fused     <<<dim3(BSZ*128),     dim3(256), 0, stream>>>(x, xmTb, n2w, n2b, out);
}

// Round 15
// 146.479 us; speedup vs baseline: 1.1115x; 1.0012x over previous
//
#include <hip/hip_runtime.h>
#include <math.h>

#define BSZ 2
#define LSEQ 2048
#define DMODEL 512
#define DINNER 1024
#define NST 16
#define RDT 32
#define GDBL 64   // RDT + 2*NST
#define NCH 32    // chunks over L
#define CHL 64    // steps per chunk
#define LOG2E 1.4426950408889634f
#define LN2   0.6931471805599453f

typedef unsigned short u16;
typedef unsigned int   u32;
typedef __attribute__((ext_vector_type(8))) __bf16 bf16x8;
typedef __attribute__((ext_vector_type(4))) float  f32x4;

__device__ __forceinline__ u16 f2bf(float f){
  u32 u = __float_as_uint(f);
  u += 0x7fff + ((u >> 16) & 1);
  return (u16)(u >> 16);
}
__device__ __forceinline__ float bf2f(u16 u){ return __uint_as_float((u32)u << 16); }
__device__ __forceinline__ float exp2fast(float x){
  float r; asm("v_exp_f32 %0, %1" : "=v"(r) : "v"(x)); return r;
}
__device__ __forceinline__ float log2fast(float x){
  float r; asm("v_log_f32 %0, %1" : "=v"(r) : "v"(x)); return r;
}
__device__ __forceinline__ float rcpfast(float x){
  float r; asm("v_rcp_f32 %0, %1" : "=v"(r) : "v"(x)); return r;
}
// silu(x) = x * rcp(1 + 2^(-x*log2e))
__device__ __forceinline__ float siluf(float x){
  return x * rcpfast(1.f + exp2fast(-x*LOG2E));
}
// softplus(x) = log2(1 + 2^(x*log2e)) * ln2
__device__ __forceinline__ float softplusf(float x){
  if (x > 20.f) return x;
  return log2fast(1.f + exp2fast(x*LOG2E)) * LN2;
}
// async global->LDS, 16B per lane
__device__ __forceinline__ void gld16(const void* g, void* l){
  __builtin_amdgcn_global_load_lds((const __attribute__((address_space(1))) void*)g,
                                   (__attribute__((address_space(3))) void*)l, 16, 0, 0);
}
// unpack 8 packed bf16 (uint4) -> 8 f32
__device__ __forceinline__ void unpack8(uint4 v, float* f){
  f[0]=__uint_as_float(v.x<<16); f[1]=__uint_as_float(v.x&0xffff0000u);
  f[2]=__uint_as_float(v.y<<16); f[3]=__uint_as_float(v.y&0xffff0000u);
  f[4]=__uint_as_float(v.z<<16); f[5]=__uint_as_float(v.z&0xffff0000u);
  f[6]=__uint_as_float(v.w<<16); f[7]=__uint_as_float(v.w&0xffff0000u);
}
// sum across the 4 lanes of a quad: 2 DPP quad_perm adds
__device__ __forceinline__ float quadsum(float p){
  p += __int_as_float(__builtin_amdgcn_update_dpp(0, __float_as_int(p), 0xB1, 0xf, 0xf, true)); // [1,0,3,2]
  p += __int_as_float(__builtin_amdgcn_update_dpp(0, __float_as_int(p), 0x4E, 0xf, 0xf, true)); // [2,3,0,1]
  return p;
}

// ---------------- K01: weight cvt (blocks 0..1631) + LN1 norm (blocks 1632..1759) ----------------
__global__ void k01_wcvt_ln(const float* __restrict__ Wip, const float* __restrict__ Wop,
                            const float* __restrict__ Wxp, const float* __restrict__ Wdt,
                            u16* __restrict__ wipb, u16* __restrict__ wopb,
                            u16* __restrict__ wxpb, u16* __restrict__ wdtb,
                            const float* __restrict__ x, const float* __restrict__ w1,
                            const float* __restrict__ b1, u16* __restrict__ xnb){
  __shared__ float ss[8][33], qq[8][33];
  __shared__ float muL[32], rsL[32];
  if (blockIdx.x < 1632){
    int idx = blockIdx.x*256 + threadIdx.x;
    int i4 = idx * 4;
    const float* src; u16* dst;
    if (i4 < 1048576){ src = Wip + i4; dst = wipb + i4; }
    else if (i4 < 1048576 + 524288){ int j = i4 - 1048576; src = Wop + j; dst = wopb + j; }
    else if (i4 < 1048576 + 524288 + 65536){ int j = i4 - 1048576 - 524288; src = Wxp + j; dst = wxpb + j; }
    else { int j = i4 - 1048576 - 524288 - 65536; if (j >= 32768) return; src = Wdt + j; dst = wdtb + j; }
    float4 v = *(const float4*)src;
    u32 lo = (u32)f2bf(v.x) | ((u32)f2bf(v.y) << 16);
    u32 hi = (u32)f2bf(v.z) | ((u32)f2bf(v.w) << 16);
    *(uint2*)dst = make_uint2(lo, hi);
    return;
  }
  // LN1: 128 blocks of 32 l; 32 lc x 8 dc (64 d each)
  int blk = blockIdx.x - 1632;
  int b = blk >> 6;
  int l0 = (blk & 63) * 32;
  int t = threadIdx.x;
  int lc = t & 31, dc = t >> 5;
  const float* xb = x + (size_t)b*DMODEL*LSEQ;
  float s=0.f, q=0.f;
  for (int d = dc*64; d < dc*64+64; ++d){
    float v = xb[d*LSEQ + l0 + lc];
    s += v; q += v*v;
  }
  ss[dc][lc]=s; qq[dc][lc]=q;
  __syncthreads();
  if (t < 32){
    float S=0.f,Q=0.f;
    for (int i=0;i<8;++i){S+=ss[i][t];Q+=qq[i][t];}
    float m = S/DMODEL;
    muL[t]=m; rsL[t]=rsqrtf(Q/DMODEL - m*m + 1e-5f);
  }
  __syncthreads();
  float mu = muL[lc], rs = rsL[lc];
  u16* orow = xnb + ((size_t)(b*LSEQ + l0 + lc))*DMODEL;
  for (int d = dc*64; d < dc*64+64; d += 2){
    float v0 = (xb[d*LSEQ + l0 + lc]     - mu)*rs*w1[d]   + b1[d];
    float v1 = (xb[(d+1)*LSEQ + l0 + lc] - mu)*rs*w1[d+1] + b1[d+1];
    *(u32*)&orow[d] = (u32)f2bf(v0) | ((u32)f2bf(v1) << 16);
  }
}

// ---------------- K2: in_proj bf16 MFMA GEMM, BK=64 (8 K-steps) ----------------
__global__ __launch_bounds__(256) void k2_inproj_mfma(
    const u16* __restrict__ xnb, const u16* __restrict__ wipb,
    u16* __restrict__ xinb, u16* __restrict__ zb){
  __shared__ u16 As[2][8192];   // 128 rows x 64 k
  __shared__ u16 Bs[2][8192];
  int t = threadIdx.x;
  int wid = t >> 6, lane = t & 63;
  int n0 = blockIdx.x * 128, m0 = blockIdx.y * 128;
  int wr = wid >> 1, wc = wid & 1;
  int lr = lane & 15, q = lane >> 4;

  const u16* gA = xnb  + (size_t)(m0 + (t>>3))*DMODEL + (t&7)*8;
  const u16* gB = wipb + (size_t)(n0 + (t>>3))*DMODEL + (t&7)*8;

  f32x4 acc[4][4];
  #pragma unroll
  for (int i=0;i<4;++i)
    #pragma unroll
    for (int j=0;j<4;++j) acc[i][j] = (f32x4){0.f,0.f,0.f,0.f};

  #pragma unroll
  for (int r=0;r<4;++r){
    gld16(gA + (size_t)r*32*DMODEL, &As[0][r*2048 + wid*512]);
    gld16(gB + (size_t)r*32*DMODEL, &Bs[0][r*2048 + wid*512]);
  }
  const int abase = (wr*64 + lr)*64 + q*8;
  const int bbase = (wc*64 + lr)*64 + q*8;

  for (int ks = 0; ks < 8; ++ks){
    int cur = ks & 1;
    __syncthreads();
    if (ks < 7){
      const u16* gA2 = gA + (ks+1)*64;
      const u16* gB2 = gB + (ks+1)*64;
      #pragma unroll
      for (int r=0;r<4;++r){
        gld16(gA2 + (size_t)r*32*DMODEL, &As[cur^1][r*2048 + wid*512]);
        gld16(gB2 + (size_t)r*32*DMODEL, &Bs[cur^1][r*2048 + wid*512]);
      }
    }
    bf16x8 a[4][2], bv[4][2];
    #pragma unroll
    for (int mf=0; mf<4; ++mf)
      #pragma unroll
      for (int s=0; s<2; ++s) a[mf][s] = *(const bf16x8*)&As[cur][abase + mf*1024 + s*32];
    #pragma unroll
    for (int nf=0; nf<4; ++nf)
      #pragma unroll
      for (int s=0; s<2; ++s) bv[nf][s] = *(const bf16x8*)&Bs[cur][bbase + nf*1024 + s*32];
    #pragma unroll
    for (int s=0; s<2; ++s)
      #pragma unroll
      for (int mf=0; mf<4; ++mf)
        #pragma unroll
        for (int nf=0; nf<4; ++nf)
          acc[mf][nf] = __builtin_amdgcn_mfma_f32_16x16x32_bf16(a[mf][s], bv[nf][s], acc[mf][nf], 0, 0, 0);
  }

  bool half = (n0 >= DINNER);
  u16* outp = half ? zb : xinb;
  int colb = (half ? n0 - DINNER : n0) + wc*64 + lr;
  #pragma unroll
  for (int mf=0; mf<4; ++mf){
    int rowb = m0 + wr*64 + mf*16 + q*4;
    #pragma unroll
    for (int nf=0; nf<4; ++nf){
      f32x4 v = acc[mf][nf];
      int col = colb + nf*16;
      #pragma unroll
      for (int j=0;j<4;++j) outp[(size_t)(rowb+j)*DINNER + col] = f2bf(v[j]);
    }
  }
}

// ---------------- K3: causal depthwise conv (K=4) + SiLU, bf16 in -> bf16 out ----------------
__global__ void k3_conv(const u16* __restrict__ xinb, const float* __restrict__ cw,
                        const float* __restrict__ cb, u16* __restrict__ xc){
  int idx = blockIdx.x*blockDim.x + threadIdx.x;
  int e4 = (idx & (DINNER/4 - 1)) * 4;
  int m = idx >> 8;
  int b = m >> 11; int l = m & (LSEQ-1);
  float4 accb = *(const float4*)&cb[e4];
  float acc[4] = {accb.x, accb.y, accb.z, accb.w};
  #pragma unroll
  for (int k=0;k<4;++k){
    int li = l + k - 3;
    if (li >= 0){
      ushort4 v = *(const ushort4*)&xinb[((size_t)(b*LSEQ+li))*DINNER + e4];
      acc[0] += bf2f(v.x) * cw[(e4+0)*4 + k];
      acc[1] += bf2f(v.y) * cw[(e4+1)*4 + k];
      acc[2] += bf2f(v.z) * cw[(e4+2)*4 + k];
      acc[3] += bf2f(v.w) * cw[(e4+3)*4 + k];
    }
  }
  u32 lo = (u32)f2bf(siluf(acc[0])) | ((u32)f2bf(siluf(acc[1])) << 16);
  u32 hi = (u32)f2bf(siluf(acc[2])) | ((u32)f2bf(siluf(acc[3])) << 16);
  *(uint2*)&xc[(size_t)m*DINNER + e4] = make_uint2(lo, hi);
}

// ---------------- K4: x_proj bf16 MFMA GEMM, BK=128 (8 K-steps); +bf16 dt_lo side out ----------------
__global__ __launch_bounds__(256) void k4_xproj_mfma(
    const u16* __restrict__ xcbf, const u16* __restrict__ wxpb,
    float* __restrict__ dbl, u16* __restrict__ dtlob){
  __shared__ u16 As[2][8192];   // [s<4][64 rows][32 k]
  __shared__ u16 Bs[2][8192];
  int t = threadIdx.x;
  int wid = t >> 6, lane = t & 63;
  int m0 = blockIdx.x * 64;
  int wr = wid >> 1, wc = wid & 1;
  int lr = lane & 15, q = lane >> 4;

  const u16* gA = xcbf + (size_t)(m0 + (t>>2))*DINNER + (t&3)*8;
  const u16* gB = wxpb + (size_t)(t>>2)*DINNER + (t&3)*8;

  f32x4 acc[2][2];
  #pragma unroll
  for (int i=0;i<2;++i)
    #pragma unroll
    for (int j=0;j<2;++j) acc[i][j] = (f32x4){0.f,0.f,0.f,0.f};

  #pragma unroll
  for (int s=0;s<4;++s){
    gld16(gA + s*32, &As[0][s*2048 + wid*512]);
    gld16(gB + s*32, &Bs[0][s*2048 + wid*512]);
  }
  const int abase = (wr*32 + lr)*32 + q*8;
  const int bbase = (wc*32 + lr)*32 + q*8;

  for (int ks = 0; ks < 8; ++ks){
    int cur = ks & 1;
    __syncthreads();
    if (ks < 7){
      const u16* gA2 = gA + (ks+1)*128;
      const u16* gB2 = gB + (ks+1)*128;
      #pragma unroll
      for (int s=0;s<4;++s){
        gld16(gA2 + s*32, &As[cur^1][s*2048 + wid*512]);
        gld16(gB2 + s*32, &Bs[cur^1][s*2048 + wid*512]);
      }
    }
    bf16x8 a[2][4], bv[2][4];
    #pragma unroll
    for (int mf=0; mf<2; ++mf)
      #pragma unroll
      for (int s=0; s<4; ++s) a[mf][s] = *(const bf16x8*)&As[cur][abase + mf*512 + s*2048];
    #pragma unroll
    for (int nf=0; nf<2; ++nf)
      #pragma unroll
      for (int s=0; s<4; ++s) bv[nf][s] = *(const bf16x8*)&Bs[cur][bbase + nf*512 + s*2048];
    #pragma unroll
    for (int s=0; s<4; ++s)
      #pragma unroll
      for (int mf=0; mf<2; ++mf)
        #pragma unroll
        for (int nf=0; nf<2; ++nf)
          acc[mf][nf] = __builtin_amdgcn_mfma_f32_16x16x32_bf16(a[mf][s], bv[nf][s], acc[mf][nf], 0, 0, 0);
  }

  #pragma unroll
  for (int mf=0; mf<2; ++mf){
    int rowb = m0 + wr*32 + mf*16 + q*4;
    #pragma unroll
    for (int nf=0; nf<2; ++nf){
      f32x4 v = acc[mf][nf];
      int col = wc*32 + nf*16 + lr;
      #pragma unroll
      for (int j=0;j<4;++j) dbl[(size_t)(rowb+j)*GDBL + col] = v[j];
      if (wc == 0){
        #pragma unroll
        for (int j=0;j<4;++j) dtlob[(size_t)(rowb+j)*RDT + col] = f2bf(v[j]);
      }
    }
  }
}

// ---------------- K5: dt_proj bf16 MFMA GEMM + softplus -> dtb (B,L,E) bf16 ----------------
__global__ __launch_bounds__(256) void k5_dtproj_mfma(
    const u16* __restrict__ dtlob, const u16* __restrict__ wdtb,
    const float* __restrict__ dtbias, u16* __restrict__ dtb){
  __shared__ u16 As[2048];
  __shared__ u16 Bs[2048];
  int t = threadIdx.x;
  int wid = t >> 6, lane = t & 63;
  int m0 = blockIdx.x * 64, d0 = blockIdx.y * 64;
  int wr = wid >> 1, wc = wid & 1;
  int lr = lane & 15, q = lane >> 4;

  gld16(dtlob + (size_t)(m0 + (t>>2))*RDT + (t&3)*8, &As[wid*512]);
  gld16(wdtb  + (size_t)(d0 + (t>>2))*RDT + (t&3)*8, &Bs[wid*512]);
  __syncthreads();

  f32x4 acc[2][2];
  bf16x8 a[2], bv[2];
  #pragma unroll
  for (int mf=0; mf<2; ++mf) a[mf]  = *(const bf16x8*)&As[(wr*32 + mf*16 + lr)*32 + q*8];
  #pragma unroll
  for (int nf=0; nf<2; ++nf) bv[nf] = *(const bf16x8*)&Bs[(wc*32 + nf*16 + lr)*32 + q*8];
  #pragma unroll
  for (int mf=0; mf<2; ++mf)
    #pragma unroll
    for (int nf=0; nf<2; ++nf)
      acc[mf][nf] = __builtin_amdgcn_mfma_f32_16x16x32_bf16(a[mf], bv[nf], (f32x4){0.f,0.f,0.f,0.f}, 0, 0, 0);

  #pragma unroll
  for (int nf=0; nf<2; ++nf){
    int col = d0 + wc*32 + nf*16 + lr;
    float bias = dtbias[col];
    #pragma unroll
    for (int mf=0; mf<2; ++mf){
      int rowb = m0 + wr*32 + mf*16 + q*4;
      f32x4 v = acc[mf][nf];
      #pragma unroll
      for (int j=0;j<4;++j) dtb[(size_t)(rowb+j)*DINNER + col] = f2bf(softplusf(v[j] + bias));
    }
  }
}

// ---------------- K6a pass1: chunk summaries; 64d x 4ng threads, 4 h-states/thread ----------------
__global__ __launch_bounds__(256) void k6a_pass1(
    const float* __restrict__ dblg, const u16* __restrict__ xcg, const u16* __restrict__ dtg,
    const float* __restrict__ Alog,
    float* __restrict__ hend, float* __restrict__ dchunk){
  int blk = blockIdx.x;
  int b = blk >> 9;
  int dblk = (blk >> 5) & 15;
  int chunk = blk & 31;
  int d0 = dblk * 64;
  int t = threadIdx.x;
  int d = t >> 2, ng = t & 3;

  float4 Adn2;
  {
    float4 al = *(const float4*)&Alog[(d0+d)*NST + ng*4];
    Adn2.x = -__expf(al.x)*LOG2E; Adn2.y = -__expf(al.y)*LOG2E;
    Adn2.z = -__expf(al.z)*LOG2E; Adn2.w = -__expf(al.w)*LOG2E;
  }
  float h0=0.f, h1=0.f, h2=0.f, h3=0.f, S=0.f;

  __shared__ float dts[32][64];
  __shared__ float xcs[32][64];
  __shared__ float Bst[32][16];

  for (int sub = 0; sub < CHL/32; ++sub){
    int l0 = chunk*CHL + sub*32;
    __syncthreads();
    { // stage dt, xc (bf16x8), B
      int r = t >> 3, c8 = t & 7;
      size_t row = (size_t)(b*LSEQ + l0 + r);
      uint4 dv = *(const uint4*)&dtg[row*DINNER + d0 + c8*8];
      uint4 xv = *(const uint4*)&xcg[row*DINNER + d0 + c8*8];
      float df[8], xf[8];
      unpack8(dv, df); unpack8(xv, xf);
      *(float4*)&dts[r][c8*8]   = make_float4(df[0],df[1],df[2],df[3]);
      *(float4*)&dts[r][c8*8+4] = make_float4(df[4],df[5],df[6],df[7]);
      *(float4*)&xcs[r][c8*8]   = make_float4(xf[0],xf[1],xf[2],xf[3]);
      *(float4*)&xcs[r][c8*8+4] = make_float4(xf[4],xf[5],xf[6],xf[7]);
      if (t < 128){
        int rB = t >> 2, qB = t & 3;
        *(float4*)&Bst[rB][qB*4] = *(const float4*)&dblg[((size_t)(b*LSEQ + l0 + rB))*GDBL + RDT + qB*4];
      }
    }
    __syncthreads();
    #pragma unroll 4
    for (int r = 0; r < 32; ++r){
      float dtv = dts[r][d];
      float xcv = xcs[r][d];
      float4 Bv = *(const float4*)&Bst[r][ng*4];
      float u = dtv * xcv;
      h0 = exp2fast(dtv*Adn2.x)*h0 + u*Bv.x;
      h1 = exp2fast(dtv*Adn2.y)*h1 + u*Bv.y;
      h2 = exp2fast(dtv*Adn2.z)*h2 + u*Bv.z;
      h3 = exp2fast(dtv*Adn2.w)*h3 + u*Bv.w;
      S += dtv;
    }
  }
  size_t cix = ((size_t)(b*NCH + chunk)*DINNER + d0 + d)*NST + ng*4;
  *(float4*)&hend[cix]   = make_float4(h0, h1, h2, h3);
  *(float4*)&dchunk[cix] = make_float4(exp2fast(Adn2.x*S), exp2fast(Adn2.y*S),
                                       exp2fast(Adn2.z*S), exp2fast(Adn2.w*S));
}

// ---------------- K6c pass2: seeded scan; bf16 LDS staging (20KB, 7 blk/CU); gated bf16 y ----------------
__global__ __launch_bounds__(256) void k6c_pass2(
    const float* __restrict__ dblg, const u16* __restrict__ xcg, const u16* __restrict__ zg,
    const u16* __restrict__ dtg,
    const float* __restrict__ Alog, const float* __restrict__ Dp,
    const float* __restrict__ hend, const float* __restrict__ dchk,
    u16* __restrict__ ybf){
  int blk = blockIdx.x;
  int b = blk >> 9;
  int dblk = (blk >> 5) & 15;
  int chunk = blk & 31;
  int d0 = dblk * 64;
  int t = threadIdx.x;
  int d = t >> 2, ng = t & 3;

  float4 Adn2;
  {
    float4 al = *(const float4*)&Alog[(d0+d)*NST + ng*4];
    Adn2.x = -__expf(al.x)*LOG2E; Adn2.y = -__expf(al.y)*LOG2E;
    Adn2.z = -__expf(al.z)*LOG2E; Adn2.w = -__expf(al.w)*LOG2E;
  }

  // inline h0: exclusive prefix over chunk summaries (float4 per step)
  float h0=0.f, h1=0.f, h2=0.f, h3=0.f;
  {
    size_t base = ((size_t)(b*NCH)*DINNER + d0 + d)*NST + ng*4;
    for (int c = 0; c < chunk; ++c){
      size_t ix = base + (size_t)c*DINNER*NST;
      float4 hv = *(const float4*)&hend[ix];
      float4 dv = *(const float4*)&dchk[ix];
      h0 = dv.x*h0 + hv.x; h1 = dv.y*h1 + hv.y;
      h2 = dv.z*h2 + hv.z; h3 = dv.w*h3 + hv.w;
    }
  }

  __shared__ u16  dts16[32][64];   // bf16 staging (raw copy; unpack on read)
  __shared__ u16  xcs16[32][64];
  __shared__ float BCs[32][32];    // B cols 0..15, C cols 16..31
  __shared__ float ys[32][64];
  __shared__ float Dps[64];

  if (t < 64) Dps[t] = Dp[d0 + t];

  for (int sub = 0; sub < CHL/32; ++sub){
    int l0 = chunk*CHL + sub*32;
    __syncthreads();
    { // stage dt, xc raw bf16 (uint4 copy), B+C fp32
      int r = t >> 3, c8 = t & 7;
      size_t row = (size_t)(b*LSEQ + l0 + r);
      *(uint4*)&dts16[r][c8*8] = *(const uint4*)&dtg[row*DINNER + d0 + c8*8];
      *(uint4*)&xcs16[r][c8*8] = *(const uint4*)&xcg[row*DINNER + d0 + c8*8];
      *(float4*)&BCs[r][c8*4]  = *(const float4*)&dblg[row*GDBL + RDT + c8*4];
    }
    __syncthreads();
    #pragma unroll 4
    for (int r = 0; r < 32; ++r){
      float dtv = bf2f(dts16[r][d]);
      float xcv = bf2f(xcs16[r][d]);
      float4 Bv = *(const float4*)&BCs[r][ng*4];
      float4 Cv = *(const float4*)&BCs[r][16 + ng*4];
      float u = dtv * xcv;
      h0 = exp2fast(dtv*Adn2.x)*h0 + u*Bv.x;
      h1 = exp2fast(dtv*Adn2.y)*h1 + u*Bv.y;
      h2 = exp2fast(dtv*Adn2.z)*h2 + u*Bv.z;
      h3 = exp2fast(dtv*Adn2.w)*h3 + u*Bv.w;
      float p = h0*Cv.x + h1*Cv.y + h2*Cv.z + h3*Cv.w;
      p = quadsum(p);
      if (ng == 0) ys[r][d] = p;
    }
    __syncthreads();
    { // gate + bf16 write (B,L,E)
      int r = t >> 3, c8 = t & 7;
      size_t row = (size_t)(b*LSEQ + l0 + r);
      uint4 zv = *(const uint4*)&zg[row*DINNER + d0 + c8*8];
      uint4 xv = *(const uint4*)&xcs16[r][c8*8];
      float zf[8], xf[8];
      unpack8(zv, zf); unpack8(xv, xf);
      float4 s0 = *(const float4*)&ys[r][c8*8];
      float4 s1 = *(const float4*)&ys[r][c8*8+4];
      float4 D0 = *(const float4*)&Dps[c8*8];
      float4 D1 = *(const float4*)&Dps[c8*8+4];
      float y0 = (s0.x + xf[0]*D0.x)*siluf(zf[0]);
      float y1 = (s0.y + xf[1]*D0.y)*siluf(zf[1]);
      float y2 = (s0.z + xf[2]*D0.z)*siluf(zf[2]);
      float y3 = (s0.w + xf[3]*D0.w)*siluf(zf[3]);
      float y4 = (s1.x + xf[4]*D1.x)*siluf(zf[4]);
      float y5 = (s1.y + xf[5]*D1.y)*siluf(zf[5]);
      float y6 = (s1.z + xf[6]*D1.z)*siluf(zf[6]);
      float y7 = (s1.w + xf[7]*D1.w)*siluf(zf[7]);
      uint4 o;
      o.x = (u32)f2bf(y0) | ((u32)f2bf(y1) << 16);
      o.y = (u32)f2bf(y2) | ((u32)f2bf(y3) << 16);
      o.z = (u32)f2bf(y4) | ((u32)f2bf(y5) << 16);
      o.w = (u32)f2bf(y6) | ((u32)f2bf(y7) << 16);
      *(uint4*)&ybf[row*DINNER + d0 + c8*8] = o;
    }
  }
}

// ---------------- K7: out_proj bf16 MFMA GEMM, BK=128 (8 K-steps), bf16 transposed out ----------------
__global__ __launch_bounds__(256) void k7_outproj_mfma(
    const u16* __restrict__ ybf, const u16* __restrict__ wopb, u16* __restrict__ xmTb){
  __shared__ u16 As[2][8192];   // [s<4][64 rows][32 k]
  __shared__ u16 Bs[2][8192];
  int t = threadIdx.x;
  int wid = t >> 6, lane = t & 63;
  int n0 = blockIdx.x * 64, m0 = blockIdx.y * 64;
  int b  = m0 >> 11;
  int l0 = m0 & (LSEQ-1);
  int wr = wid >> 1, wc = wid & 1;
  int lr = lane & 15, q = lane >> 4;

  const u16* gA = ybf  + (size_t)(m0 + (t>>2))*DINNER + (t&3)*8;
  const u16* gB = wopb + (size_t)(n0 + (t>>2))*DINNER + (t&3)*8;

  f32x4 acc[2][2];
  #pragma unroll
  for (int i=0;i<2;++i)
    #pragma unroll
    for (int j=0;j<2;++j) acc[i][j] = (f32x4){0.f,0.f,0.f,0.f};

  #pragma unroll
  for (int s=0;s<4;++s){
    gld16(gA + s*32, &As[0][s*2048 + wid*512]);
    gld16(gB + s*32, &Bs[0][s*2048 + wid*512]);
  }
  const int abase = (wr*32 + lr)*32 + q*8;
  const int bbase = (wc*32 + lr)*32 + q*8;

  for (int ks = 0; ks < 8; ++ks){
    int cur = ks & 1;
    __syncthreads();
    if (ks < 7){
      const u16* gA2 = gA + (ks+1)*128;
      const u16* gB2 = gB + (ks+1)*128;
      #pragma unroll
      for (int s=0;s<4;++s){
        gld16(gA2 + s*32, &As[cur^1][s*2048 + wid*512]);
        gld16(gB2 + s*32, &Bs[cur^1][s*2048 + wid*512]);
      }
    }
    bf16x8 a[2][4], bv[2][4];
    #pragma unroll
    for (int mf=0; mf<2; ++mf)
      #pragma unroll
      for (int s=0; s<4; ++s) a[mf][s] = *(const bf16x8*)&As[cur][abase + mf*512 + s*2048];
    #pragma unroll
    for (int nf=0; nf<2; ++nf)
      #pragma unroll
      for (int s=0; s<4; ++s) bv[nf][s] = *(const bf16x8*)&Bs[cur][bbase + nf*512 + s*2048];
    #pragma unroll
    for (int s=0; s<4; ++s)
      #pragma unroll
      for (int mf=0; mf<2; ++mf)
        #pragma unroll
        for (int nf=0; nf<2; ++nf)
          acc[mf][nf] = __builtin_amdgcn_mfma_f32_16x16x32_bf16(a[mf][s], bv[nf][s], acc[mf][nf], 0, 0, 0);
  }

  // transposed bf16 store: 4 acc elements = 4 consecutive l -> one uint2 (8B)
  #pragma unroll
  for (int mf=0; mf<2; ++mf){
    int lrow = l0 + wr*32 + mf*16 + q*4;
    #pragma unroll
    for (int nf=0; nf<2; ++nf){
      f32x4 v = acc[mf][nf];
      int col = n0 + wc*32 + nf*16 + lr;
      u32 lo = (u32)f2bf(v[0]) | ((u32)f2bf(v[1]) << 16);
      u32 hi = (u32)f2bf(v[2]) | ((u32)f2bf(v[3]) << 16);
      *(uint2*)&xmTb[((size_t)(b*DMODEL + col))*LSEQ + lrow] = make_uint2(lo, hi);
    }
  }
}

// ---------------- K8: fused LN2 (stats + apply), 16-l blocks ----------------
__global__ void k8_fused(const float* __restrict__ x, const u16* __restrict__ xmTb,
                         const float* __restrict__ w2, const float* __restrict__ b2,
                         float* __restrict__ out){
  int blk = blockIdx.x;
  int b = blk >> 7;
  int l0 = (blk & 127) * 16;
  int t = threadIdx.x;
  int lc = t & 15, dc = t >> 4;
  const float* xb = x    + (size_t)b*DMODEL*LSEQ + l0 + lc;
  const u16*   xt = xmTb + (size_t)b*DMODEL*LSEQ + l0 + lc;
  float s=0.f, q=0.f;
  for (int d = dc*32; d < dc*32+32; ++d){
    float v = xb[d*LSEQ] + bf2f(xt[d*LSEQ]);
    s += v; q += v*v;
  }
  __shared__ float ss[16][17], qq[16][17];
  __shared__ float muL[16], rsL[16];
  ss[dc][lc]=s; qq[dc][lc]=q;
  __syncthreads();
  if (t < 16){
    float S=0.f,Q=0.f;
    for (int i=0;i<16;++i){S+=ss[i][t];Q+=qq[i][t];}
    float m = S/DMODEL;
    muL[t]=m; rsL[t]=rsqrtf(Q/DMODEL - m*m + 1e-5f);
  }
  __syncthreads();
  float mu = muL[lc], rs = rsL[lc];
  float* ob = out + (size_t)b*DMODEL*LSEQ + l0 + lc;
  for (int d = dc*32; d < dc*32+32; ++d){
    float v = xb[d*LSEQ] + bf2f(xt[d*LSEQ]);
    ob[d*LSEQ] = (v - mu)*rs*w2[d] + b2[d];
  }
}

extern "C" void kernel_launch(void* const* d_in, const int* in_sizes, int n_in,
                              void* d_out, int out_size, void* d_ws, size_t ws_size,
                              hipStream_t stream) {
  const float* x      = (const float*)d_in[0];
  const float* n1w    = (const float*)d_in[1];
  const float* n1b    = (const float*)d_in[2];
  const float* n2w    = (const float*)d_in[3];
  const float* n2b    = (const float*)d_in[4];
  const float* Wip    = (const float*)d_in[5];
  const float* cw     = (const float*)d_in[6];
  const float* cb     = (const float*)d_in[7];
  const float* Wxp    = (const float*)d_in[8];
  const float* Wdt    = (const float*)d_in[9];
  const float* dtbias = (const float*)d_in[10];
  const float* Alog   = (const float*)d_in[11];
  const float* Dp     = (const float*)d_in[12];
  const float* Wop    = (const float*)d_in[13];
  float* out = (float*)d_out;

  // Workspace layout (float offsets), ~62 MB total
  float* ws = (float*)d_ws;
  size_t o = 0;
  u16*  xinb = (u16*)(ws + o); o += 2097152;   // (B,L,E) bf16
  u16*  zb   = (u16*)(ws + o); o += 2097152;   // (B,L,E) bf16
  u16*  xcb  = (u16*)(ws + o); o += 2097152;   // (B,L,E) bf16
  u16*  ybf  = (u16*)(ws + o); o += 2097152;   // (B,L,E) bf16
  u16*  dtb  = (u16*)(ws + o); o += 2097152;   // (B,L,E) bf16 dt
  u16*  xnb  = (u16*)(ws + o); o += 1048576;   // (B,L,D) bf16
  u16*  wipb = (u16*)(ws + o); o += 524288;    // (2048,512) bf16
  u16*  wopb = (u16*)(ws + o); o += 262144;    // (512,1024) bf16
  u16*  wxpb = (u16*)(ws + o); o += 32768;     // (64,1024) bf16
  u16*  wdtb = (u16*)(ws + o); o += 16384;     // (1024,32) bf16
  u16*  dtlob= (u16*)(ws + o); o += 65536;     // (B,L,32) bf16
  float* dbl  = ws + o; o += 262144;           // (B,L,64) fp32
  float* hend = ws + o; o += 1048576;          // (B,NCH,E,NST)
  float* dchk = ws + o; o += 1048576;
  u16*  xmTb  = (u16*)(ws + o); o += 1048576;  // (B,DMODEL,L) bf16

  k01_wcvt_ln  <<<dim3(1760),        dim3(256), 0, stream>>>(Wip, Wop, Wxp, Wdt, wipb, wopb, wxpb, wdtb,
                                                             x, n1w, n1b, xnb);
  k2_inproj_mfma<<<dim3(16,32),      dim3(256), 0, stream>>>(xnb, wipb, xinb, zb);
  k3_conv      <<<dim3(4096),        dim3(256), 0, stream>>>(xinb, cw, cb, xcb);
  k4_xproj_mfma<<<dim3(64),          dim3(256), 0, stream>>>(xcb, wxpb, dbl, dtlob);
  k5_dtproj_mfma<<<dim3(64,16),      dim3(256), 0, stream>>>(dtlob, wdtb, dtbias, dtb);
  k6a_pass1    <<<dim3(BSZ*16*NCH),  dim3(256), 0, stream>>>(dbl, xcb, dtb, Alog, hend, dchk);
  k6c_pass2    <<<dim3(BSZ*16*NCH),  dim3(256), 0, stream>>>(dbl, xcb, zb, dtb, Alog, Dp, hend, dchk, ybf);
  k7_outproj_mfma<<<dim3(8,64),      dim3(256), 0, stream>>>(ybf, wopb, xmTb);
  k8_fused     <<<dim3(BSZ*128),     dim3(256), 0, stream>>>(x, xmTb, n2w, n2b, out);
}